// Round 14
// baseline (396.944 us; speedup 1.0000x reference)
//
#include <hip/hip_runtime.h>
#include <hip/hip_bf16.h>
#include <hip/hip_fp8.h>
#include <stdint.h>

typedef unsigned short ushort_t;
typedef __attribute__((ext_vector_type(16))) float f32x16;

#define DEV __device__ __forceinline__

DEV int refl(int j) { return j < 0 ? -j : (j > 63 ? 126 - j : j); }

DEV void gload_lds16(const void* g, void* l) {
  __builtin_amdgcn_global_load_lds(
      (const __attribute__((address_space(1))) unsigned int*)g,
      (__attribute__((address_space(3))) unsigned int*)l, 16, 0, 0);
}

// packed candidate: monotone top-20 bits of float | 12-bit row index
DEV unsigned packval(float v, int idx) {
  unsigned u = __float_as_uint(v);
  u ^= (0x80000000u | (unsigned)((int)u >> 31));
  return (u & 0xFFFFF000u) | (unsigned)idx;
}

// sorted-desc 8-slot insert via max/min bubble-through (16 VALU, no branches)
DEV void ins8(unsigned (&s)[8], unsigned p) {
#pragma unroll
  for (int j = 0; j < 8; ++j) {
    unsigned mx = s[j] > p ? s[j] : p;
    unsigned mn = s[j] > p ? p : s[j];
    s[j] = mx;
    p = mn;
  }
}

// --------------------------- fused NCHW->NHWC transpose + weights prep
__global__ __launch_bounds__(256) void k_prep(
    const float* __restrict__ x, float* __restrict__ xt,
    const float* __restrict__ w1, const float* __restrict__ w2,
    const float* __restrict__ wt1, const float* __restrict__ bt1,
    const float* __restrict__ wt2, const float* __restrict__ bt2,
    float* __restrict__ W1t, float* __restrict__ W2t,
    float* __restrict__ Wcat, float* __restrict__ beff) {
  int t = threadIdx.x;
  if (blockIdx.x < 256) {
    __shared__ float tile[64][65];
    int wg = blockIdx.x;
    int b = wg >> 6, pt = wg & 63;
    int lane = t & 63, grp = t >> 6;
    const float* xb = x + ((size_t)b * 64) * 4096 + pt * 64;
#pragma unroll
    for (int j = 0; j < 16; ++j) {
      int c = j * 4 + grp;
      tile[c][lane] = xb[(size_t)c * 4096 + lane];
    }
    __syncthreads();
    float* xtb = xt + ((size_t)b * 4096 + (size_t)pt * 64) * 64;
#pragma unroll
    for (int j = 0; j < 16; ++j) {
      int p = j * 4 + grp;
      xtb[p * 64 + lane] = tile[lane][p];
    }
    return;
  }
  int id = (blockIdx.x - 256) * 256 + t;
  if (id < 36864) {
    int co = id & 63, k = id >> 6;
    int tap = k >> 6, ci = k & 63;
    W1t[k * 64 + co] = w1[(co * 64 + ci) * 9 + tap];
  } else if (id < 73728) {
    int rel = id - 36864;
    int co = rel & 63, k = rel >> 6;
    int tap = k >> 6, ci = k & 63;
    W2t[k * 64 + co] = w2[(co * 64 + ci) * 9 + tap];
  } else if (id < 81920) {
    int rel = id - 73728;
    int co = rel & 63, k = rel >> 6;  // k in [0,128)
    Wcat[k * 64 + co] = wt2[co * 192 + k];
  } else if (id < 98304) {
    int rel = id - 81920;
    int co = rel & 63, j = rel >> 6;  // j in [0,256)
    float s = 0.f;
    for (int ct = 0; ct < 64; ++ct) s += wt2[co * 192 + 128 + ct] * wt1[ct * 256 + j];
    Wcat[(128 + j) * 64 + co] = s;
  } else if (id < 98368) {
    int co = id - 98304;
    float s = bt2[co];
    for (int ct = 0; ct < 64; ++ct) s += wt2[co * 192 + 128 + ct] * bt1[ct];
    beff[co] = s;
  }
}

// ------------------- unfold (reflect) -> NORMALIZED fp8-e4m3 tiled + f64 norms
// Xq layout (bytes): [b*512+rb][kc(9)][seg(4)][r8(8)][e(16)], rb=l>>3, r8=l&7,
// d = kc*64 + seg*16 + e; here kc=tap, seg=c>>4, e=c&15. rb stride = 4608 B.
__global__ __launch_bounds__(512) void k_unfold(const float* __restrict__ xt,
                                                uint8_t* __restrict__ Xq,
                                                double* __restrict__ dinv) {
  __shared__ uint8_t U[4608];
  int rbg = blockIdx.x;           // 0..2047
  int b = rbg >> 9, rb = rbg & 511;
  int t = threadIdx.x;
  int p = t >> 6, lane = t & 63;
  int l = rb * 8 + p;
  int y = l >> 6, xq = l & 63;
  const float* xb = xt + ((size_t)b * 4096) * 64;
  float v[9];
  double s = 0.0;
#pragma unroll
  for (int tap = 0; tap < 9; ++tap) {
    int kh = tap / 3, kw = tap % 3;
    int gy = refl(y + kh - 1), gx = refl(xq + kw - 1);
    v[tap] = xb[(gy * 64 + gx) * 64 + lane];
    s += (double)v[tap] * (double)v[tap];
  }
#pragma unroll
  for (int off = 32; off; off >>= 1) s += __shfl_xor(s, off, 64);
  double n = sqrt(s);
  if (n < 1e-12) n = 1e-12;
  if (lane == 0) dinv[b * 4096 + l] = 1.0 / n;
  float inv = (float)(1.0 / n);
#pragma unroll
  for (int tap = 0; tap < 9; ++tap) {
    __hip_fp8_e4m3 h(v[tap] * inv);
    U[tap * 512 + (lane >> 4) * 128 + p * 16 + (lane & 15)] = h.__x;
  }
  __syncthreads();
  uint8_t* g = Xq + (size_t)rbg * 4608;
  if (t < 288) *(uint4*)&g[t * 16] = *(const uint4*)&U[t * 16];
}

// ------------------------------- 3x3 conv f32, 2 pixels/thread (W amortized)
__global__ __launch_bounds__(256, 2) void k_conv3x3(const float* __restrict__ in_t,
                                                    const float* __restrict__ Wt,
                                                    const float* __restrict__ bias,
                                                    float* __restrict__ out_t,
                                                    int do_relu) {
  __shared__ float X[32][580];
  int t = threadIdx.x;
  int p0 = blockIdx.x * 32;
  int b = p0 >> 12;
  int pl = p0 & 4095;
  const float* inb = in_t + ((size_t)b * 4096) * 64;
  {
    int lane = t & 63, grp = t >> 6;
#pragma unroll
    for (int j = 0; j < 8; ++j) {
      int px = grp * 8 + j;
      int p = pl + px;
      int y = p >> 6, xq = p & 63;
#pragma unroll
      for (int tap = 0; tap < 9; ++tap) {
        int kh = tap / 3, kw = tap % 3;
        int yy = y + kh - 1, xx = xq + kw - 1;
        float v = (yy >= 0 && yy < 64 && xx >= 0 && xx < 64)
                      ? inb[(yy * 64 + xx) * 64 + lane] : 0.f;
        X[px][tap * 64 + lane] = v;
      }
    }
  }
  __syncthreads();
  int px = t & 15, cog = t >> 4;
  const float* Wp = Wt + cog * 4;
  float4 bz = *(const float4*)&bias[cog * 4];
  float a0 = bz.x, a1 = bz.y, a2 = bz.z, a3 = bz.w;
  float c0 = bz.x, c1 = bz.y, c2 = bz.z, c3 = bz.w;
#pragma unroll 2
  for (int k = 0; k < 576; k += 4) {
    float4 xa = *(const float4*)&X[px][k];
    float4 xc = *(const float4*)&X[px + 16][k];
    float4 w0 = *(const float4*)&Wp[(k + 0) * 64];
    float4 w1 = *(const float4*)&Wp[(k + 1) * 64];
    float4 w2 = *(const float4*)&Wp[(k + 2) * 64];
    float4 w3 = *(const float4*)&Wp[(k + 3) * 64];
    a0 += w0.x * xa.x + w1.x * xa.y + w2.x * xa.z + w3.x * xa.w;
    a1 += w0.y * xa.x + w1.y * xa.y + w2.y * xa.z + w3.y * xa.w;
    a2 += w0.z * xa.x + w1.z * xa.y + w2.z * xa.z + w3.z * xa.w;
    a3 += w0.w * xa.x + w1.w * xa.y + w2.w * xa.z + w3.w * xa.w;
    c0 += w0.x * xc.x + w1.x * xc.y + w2.x * xc.z + w3.x * xc.w;
    c1 += w0.y * xc.x + w1.y * xc.y + w2.y * xc.z + w3.y * xc.w;
    c2 += w0.z * xc.x + w1.z * xc.y + w2.z * xc.z + w3.z * xc.w;
    c3 += w0.w * xc.x + w1.w * xc.y + w2.w * xc.z + w3.w * xc.w;
  }
  if (do_relu) {
    a0 = fmaxf(a0, 0.f); a1 = fmaxf(a1, 0.f);
    a2 = fmaxf(a2, 0.f); a3 = fmaxf(a3, 0.f);
    c0 = fmaxf(c0, 0.f); c1 = fmaxf(c1, 0.f);
    c2 = fmaxf(c2, 0.f); c3 = fmaxf(c3, 0.f);
  }
  float4 r0; r0.x = a0; r0.y = a1; r0.z = a2; r0.w = a3;
  float4 r1; r1.x = c0; r1.y = c1; r1.z = c2; r1.w = c3;
  *(float4*)&out_t[((size_t)(p0 + px)) * 64 + cog * 4] = r0;
  *(float4*)&out_t[((size_t)(p0 + px + 16)) * 64 + cog * 4] = r1;
}

// -------- fp8 Gram, flat 36-step pipeline, shfl-free two-list top-k
// Lane keeps lown (column l, il==half regs) and loth (column l^32, il!=half).
// Both candidates of a reg share row index rbase+4*half (verified algebra).
// Final merge: 8 lists (2 halves x 4 waves) = 64 entries per column via LDS.
__global__ __launch_bounds__(256, 4) void k_gram(const uint8_t* __restrict__ Xq,
                                                 int* __restrict__ pidx) {
  __shared__ __align__(16) char lds[40960];
  uint8_t* sAb = (uint8_t*)lds;             // 2 bufs x 16KB
  uint8_t* sBb = (uint8_t*)(lds + 32768);   // 2 bufs x 4KB

  int wg = blockIdx.x;
  int u = wg & 7, v = wg >> 3;
  int bs = u + 8 * (v & 1);        // (b,sp) group: 2 per XCD
  int b = bs >> 2, sp = bs & 3;
  int cb = v >> 1;                 // 0..63
  int colbase = cb * 64;
  int t = threadIdx.x;
  int w = t >> 6, lane = t & 63;
  int rr = lane & 31, half = lane >> 5;

  const uint8_t* Xb = Xq + (size_t)b * 512 * 4608;
  const uint8_t* XB = Xb + (size_t)(cb * 8) * 4608;
  const uint8_t* XAroot = Xb + (size_t)(sp * 128) * 4608;

  unsigned lown[8], loth[8];
#pragma unroll
  for (int j = 0; j < 8; ++j) { lown[j] = 0u; loth[j] = 0u; }

  f32x16 acc[2][2];
#pragma unroll
  for (int im = 0; im < 2; ++im)
#pragma unroll
    for (int il = 0; il < 2; ++il)
#pragma unroll
      for (int q = 0; q < 16; ++q) acc[im][il][q] = 0.f;

  // prologue: stage step 0 (mt=0, kc=0) into buf 0
  {
#pragma unroll
    for (int j = 0; j < 4; ++j) {
      int s = j * 256 + t;
      gload_lds16(XAroot + (size_t)(s >> 5) * 4608 + (s & 31) * 16, sAb + s * 16);
    }
    gload_lds16(XB + (size_t)(t >> 5) * 4608 + (t & 31) * 16, sBb + t * 16);
  }

  int pm = 0, pk = 1;   // prefetch counters (step s+1)
  int cm = 0, ck = 0;   // consume counters
#pragma unroll 1
  for (int s = 0; s < 36; ++s) {
    __syncthreads();
    if (s < 35) {
      int buf = (s + 1) & 1;
      int ko = pk * 512;
      const uint8_t* XA = XAroot + pm * (32 * 4608);
#pragma unroll
      for (int j = 0; j < 4; ++j) {
        int sl = j * 256 + t;
        gload_lds16(XA + (size_t)(sl >> 5) * 4608 + ko + (sl & 31) * 16,
                    sAb + buf * 16384 + sl * 16);
      }
      gload_lds16(XB + (size_t)(t >> 5) * 4608 + ko + (t & 31) * 16,
                  sBb + buf * 4096 + t * 16);
      ++pk;
      if (pk == 9) { pk = 0; ++pm; }
    }
    const uint8_t* tA = sAb + (s & 1) * 16384;
    const uint8_t* tB = sBb + (s & 1) * 4096;
#pragma unroll
    for (int j = 0; j < 4; ++j) {
      int so = (j * 8 + (rr & 7)) * 16 + half * 8;
      long a0 = *(const long*)&tA[((w * 8 + (rr >> 3)) * 32) * 16 + so];
      long a1 = *(const long*)&tA[((w * 8 + 4 + (rr >> 3)) * 32) * 16 + so];
      long b0 = *(const long*)&tB[(((rr >> 3)) * 32) * 16 + so];
      long b1 = *(const long*)&tB[((4 + (rr >> 3)) * 32) * 16 + so];
      acc[0][0] = __builtin_amdgcn_mfma_f32_32x32x16_fp8_fp8(a0, b0, acc[0][0], 0, 0, 0);
      acc[0][1] = __builtin_amdgcn_mfma_f32_32x32x16_fp8_fp8(a0, b1, acc[0][1], 0, 0, 0);
      acc[1][0] = __builtin_amdgcn_mfma_f32_32x32x16_fp8_fp8(a1, b0, acc[1][0], 0, 0, 0);
      acc[1][1] = __builtin_amdgcn_mfma_f32_32x32x16_fp8_fp8(a1, b1, acc[1][1], 0, 0, 0);
    }
    if (ck == 8) {
      // mt complete: two-list top-8 update, 64 candidates/lane, no shfl
      int rowb = sp * 1024 + cm * 256 + w * 64;
#pragma unroll
      for (int im = 0; im < 2; ++im) {
#pragma unroll
        for (int reg = 0; reg < 16; ++reg) {
          float a0 = acc[im][0][reg], a1 = acc[im][1][reg];
          float vo = half ? a1 : a0;   // own column (il == half)
          float vs = half ? a0 : a1;   // partner column l^32, same row
          int ridx = rowb + im * 32 + (reg & 3) + 8 * (reg >> 2) + 4 * half;
          ins8(lown, packval(vo, ridx));
          ins8(loth, packval(vs, ridx));
        }
      }
#pragma unroll
      for (int im = 0; im < 2; ++im)
#pragma unroll
        for (int il = 0; il < 2; ++il)
#pragma unroll
          for (int q = 0; q < 16; ++q) acc[im][il][q] = 0.f;
      ck = 0;
      ++cm;
    } else {
      ++ck;
    }
  }
  // merge 8 lists (2 halves x 4 waves) -> top-8 per column
  __syncthreads();
  unsigned* M = (unsigned*)lds;   // 64 cols x 66 stride
#pragma unroll
  for (int j = 0; j < 8; ++j) {
    M[lane * 66 + w * 8 + j] = lown[j];
    M[(lane ^ 32) * 66 + 32 + w * 8 + j] = loth[j];
  }
  __syncthreads();
  if (t < 64) {
    unsigned bl[8];
#pragma unroll
    for (int j = 0; j < 8; ++j) bl[j] = 0u;
#pragma unroll 1
    for (int i = 0; i < 64; ++i) ins8(bl, M[t * 66 + i]);
    size_t base = (((size_t)b * 4 + sp) * 4096 + colbase + t) * 8;
#pragma unroll
    for (int j = 0; j < 8; ++j) pidx[base + j] = (int)bl[j];
  }
}

// ---- fp8-top-8 tournament, then exact f64 refine (4 candidates/iteration
// via 16-lane quarter-groups; lane covers 4 channels with float4 gathers)
__global__ __launch_bounds__(256) void k_refine(const float* __restrict__ xt,
                                                const double* __restrict__ dinv,
                                                const int* __restrict__ pidx,
                                                float* __restrict__ Sval,
                                                int* __restrict__ Sidx) {
  int w = threadIdx.x >> 6, lane = threadIdx.x & 63;
  int gl = blockIdx.x * 4 + w;
  int b = gl >> 12, l = gl & 4095;
  int y = l >> 6, xq = l & 63;
  const float* xb = xt + ((size_t)b * 4096) * 64;
  unsigned cp = 0u;
  if (lane < 32) {
    int sp = lane >> 3, j = lane & 7;
    cp = (unsigned)pidx[(((size_t)b * 4 + sp) * 4096 + l) * 8 + j];
  }
  // tournament: top-8 by packed value (indices unique -> values unique)
  int wm[8];
#pragma unroll
  for (int r = 0; r < 8; ++r) {
    unsigned v = cp;
#pragma unroll
    for (int off = 32; off; off >>= 1) {
      unsigned ov = __shfl_xor(v, off, 64);
      v = ov > v ? ov : v;
    }
    wm[r] = (int)(v & 4095u);
    if (cp == v) cp = 0u;
  }
  // own-patch channels for this lane's quarter-group: ch = (lane&15)*4
  int ch4 = (lane & 15) * 4;
  float4 xl4[9];
#pragma unroll
  for (int tap = 0; tap < 9; ++tap) {
    int kh = tap / 3, kw = tap % 3;
    xl4[tap] = *(const float4*)&xb[(refl(y + kh - 1) * 64 + refl(xq + kw - 1)) * 64 + ch4];
  }
  double il = dinv[b * 4096 + l];
  double rv = -1e30;
  int ridx = 0x7fffffff;
#pragma unroll
  for (int it = 0; it < 2; ++it) {
    int m = wm[it * 4 + (lane >> 4)];
    int my = m >> 6, mx = m & 63;
    double d = 0.0;
#pragma unroll
    for (int tap = 0; tap < 9; ++tap) {
      int kh = tap / 3, kw = tap % 3;
      float4 gv = *(const float4*)&xb[(refl(my + kh - 1) * 64 + refl(mx + kw - 1)) * 64 + ch4];
      d += (double)xl4[tap].x * (double)gv.x + (double)xl4[tap].y * (double)gv.y +
           (double)xl4[tap].z * (double)gv.z + (double)xl4[tap].w * (double)gv.w;
    }
#pragma unroll
    for (int off = 1; off < 16; off <<= 1) d += __shfl_xor(d, off, 64);
    double R = d * il * dinv[b * 4096 + m];
    // lane r = it*4+g receives R of group g (source lane g*16)
    double Rsrc = __shfl(R, (lane & 3) * 16, 64);
    int msrc = __shfl(m, (lane & 3) * 16, 64);
    if ((lane >> 2) == it && lane < 8) { rv = Rsrc; ridx = msrc; }
  }
  // exact top-5 (rank 0 is self); emit ranks 1..4; ties -> lower index first
#pragma unroll
  for (int r = 0; r < 5; ++r) {
    double v = rv;
    int i = ridx;
#pragma unroll
    for (int off = 32; off; off >>= 1) {
      double ov = __shfl_xor(v, off, 64);
      int oi = __shfl_xor(i, off, 64);
      if (ov > v || (ov == v && oi < i)) { v = ov; i = oi; }
    }
    if (r >= 1 && lane == 0) {
      Sval[((size_t)b * 5 + r) * 4096 + l] = (float)v;
      Sidx[((size_t)b * 5 + r) * 4096 + l] = i;
    }
    if (rv == v && ridx == i) rv = -1e30;
  }
}

// ------------------------- fused fold/scale + composed 1x1 convs -> y (NCHW)
__global__ __launch_bounds__(256, 4) void k_out(const float* __restrict__ xt,
                                                const float* __restrict__ feat,
                                                const float* __restrict__ Sval,
                                                const int* __restrict__ Sidx,
                                                const float* __restrict__ Wcat,
                                                const float* __restrict__ beff,
                                                float* __restrict__ out) {
  __shared__ float X[16 * 388];   // stride 388 (16B aligned rows)
  __shared__ int SI[3 * 18 * 4];  // halo match indices, 0x7fffffff = outside
  __shared__ float SV[16 * 4];
  int t = threadIdx.x;
  int w = t >> 6, lane = t & 63;
  int p0 = blockIdx.x * 16;
  int b = p0 >> 12, pl = p0 & 4095;
  int y0 = pl >> 6, x0 = pl & 63;
  // ---- stage A: prefetch
  if (t < 216) {
    int r = t / 72, rem = t % 72;
    int c = rem >> 2, i = (rem & 3) + 1;
    int qy = y0 - 1 + r, qx = x0 - 1 + c;
    int m = 0x7fffffff;
    if (qy >= 0 && qy < 64 && qx >= 0 && qx < 64)
      m = Sidx[((size_t)b * 5 + i) * 4096 + qy * 64 + qx] & 4095;
    SI[(r * 18 + c) * 4 + (i - 1)] = m;
  }
  if (t < 64) {
    int px = t >> 2, i = (t & 3) + 1;
    SV[px * 4 + (i - 1)] = Sval[((size_t)b * 5 + i) * 4096 + pl + px];
  }
#pragma unroll
  for (int jj = 0; jj < 4; ++jj) {
    int px = w * 4 + jj;
    X[px * 388 + lane] = feat[((size_t)b * 4096 + pl + px) * 64 + lane];
    X[px * 388 + 64 + lane] = xt[((size_t)b * 4096 + pl + px) * 64 + lane];
  }
  __syncthreads();
  // ---- stage B: gathers. 64 (px,i) pairs; wave w owns pairs [16w,16w+16)
  const float* xb = xt + ((size_t)b * 4096) * 64;
#pragma unroll 4
  for (int k = 0; k < 16; ++k) {
    int pr = w * 16 + k;
    int px = pr >> 2, i = pr & 3;  // i rank-1 in 0..3
    float a = 0.f;
#pragma unroll
    for (int tap = 0; tap < 9; ++tap) {
      int kh = tap / 3, kw = tap % 3;
      int m = SI[((2 - kh) * 18 + px + 2 - kw) * 4 + i];
      if (m != 0x7fffffff) {
        int gy = refl((m >> 6) + kh - 1), gx = refl((m & 63) + kw - 1);
        a += xb[(gy * 64 + gx) * 64 + lane];
      }
    }
    X[px * 388 + 128 + i * 64 + lane] = a * SV[px * 4 + i] * (1.f / 9.f);
  }
  __syncthreads();
  // ---- stage C: matvec 384 -> 64, 4 outputs/thread, float4 X reads
  int px = t & 15, cog = t >> 4;
  float4 acc = *(const float4*)&beff[cog * 4];
#pragma unroll 2
  for (int k = 0; k < 384; k += 4) {
    float4 xv = *(const float4*)&X[px * 388 + k];
    float4 w0 = *(const float4*)&Wcat[(k + 0) * 64 + cog * 4];
    float4 w1 = *(const float4*)&Wcat[(k + 1) * 64 + cog * 4];
    float4 w2 = *(const float4*)&Wcat[(k + 2) * 64 + cog * 4];
    float4 w3 = *(const float4*)&Wcat[(k + 3) * 64 + cog * 4];
    acc.x += w0.x * xv.x + w1.x * xv.y + w2.x * xv.z + w3.x * xv.w;
    acc.y += w0.y * xv.x + w1.y * xv.y + w2.y * xv.z + w3.y * xv.w;
    acc.z += w0.z * xv.x + w1.z * xv.y + w2.z * xv.z + w3.z * xv.w;
    acc.w += w0.w * xv.x + w1.w * xv.y + w2.w * xv.z + w3.w * xv.w;
  }
  size_t ob = ((size_t)b * 64 + cog * 4) * 4096 + pl + px;
  out[ob] = acc.x;
  out[ob + 4096] = acc.y;
  out[ob + 8192] = acc.z;
  out[ob + 12288] = acc.w;
}

// ---------------------------------------------------------------------- launch
extern "C" void kernel_launch(void* const* d_in, const int* in_sizes, int n_in,
                              void* d_out, int out_size, void* d_ws, size_t ws_size,
                              hipStream_t stream) {
  const float* x = (const float*)d_in[0];
  const float* w1 = (const float*)d_in[1];
  const float* b1 = (const float*)d_in[2];
  const float* w2 = (const float*)d_in[3];
  const float* b2 = (const float*)d_in[4];
  const float* wt1 = (const float*)d_in[5];
  const float* bt1 = (const float*)d_in[6];
  const float* wt2 = (const float*)d_in[7];
  const float* bt2 = (const float*)d_in[8];

  char* ws = (char*)d_ws;
  float* x_t = (float*)(ws + 0);                       //  4 MB NHWC x
  float* y1 = (float*)(ws + 4194304);                  //  4 MB relu(conv1)
  float* feat = (float*)(ws + 8388608);                //  4 MB conv2
  uint8_t* Xq = (uint8_t*)(ws + 12582912);             //  9.4 MB fp8 qn unfold
  double* dinv = (double*)(ws + 31457280);             // 128 KB f64 1/norm
  int* pidx = (int*)(ws + 31653888);                   //  2 MB
  float* Sval = (float*)(ws + 33751040);               // 320 KB
  int* Sidx = (int*)(ws + 34078720);                   // 320 KB
  float* W1t = (float*)(ws + 34406400);                // 144 KB
  float* W2t = (float*)(ws + 34553856);                // 144 KB
  float* Wcat = (float*)(ws + 34701312);               //  96 KB
  float* beff = (float*)(ws + 34799616);               // 256 B
  float* out = (float*)d_out;

  k_prep<<<dim3(641), dim3(256), 0, stream>>>(x, x_t, w1, w2, wt1, bt1, wt2, bt2,
                                              W1t, W2t, Wcat, beff);
  k_unfold<<<dim3(2048), dim3(512), 0, stream>>>(x_t, Xq, dinv);
  k_conv3x3<<<dim3(512), dim3(256), 0, stream>>>(x_t, W1t, b1, y1, 1);
  k_conv3x3<<<dim3(512), dim3(256), 0, stream>>>(y1, W2t, b2, feat, 0);
  k_gram<<<dim3(1024), dim3(256), 0, stream>>>(Xq, pidx);
  k_refine<<<dim3(4096), dim3(256), 0, stream>>>(x_t, dinv, pidx, Sval, Sidx);
  k_out<<<dim3(1024), dim3(256), 0, stream>>>(x_t, feat, Sval, Sidx, Wcat, beff, out);
}

// Round 15
// 321.253 us; speedup vs baseline: 1.2356x; 1.2356x over previous
//
#include <hip/hip_runtime.h>
#include <hip/hip_bf16.h>
#include <hip/hip_fp8.h>
#include <stdint.h>

typedef unsigned short ushort_t;
typedef __attribute__((ext_vector_type(8))) short short8;
typedef __attribute__((ext_vector_type(16))) float f32x16;

#define DEV __device__ __forceinline__

DEV int refl(int j) { return j < 0 ? -j : (j > 63 ? 126 - j : j); }

DEV void gload_lds16(const void* g, void* l) {
  __builtin_amdgcn_global_load_lds(
      (const __attribute__((address_space(1))) unsigned int*)g,
      (__attribute__((address_space(3))) unsigned int*)l, 16, 0, 0);
}

// packed candidate: monotone top-20 bits of float | 12-bit row index
DEV unsigned packval(float v, int idx) {
  unsigned u = __float_as_uint(v);
  u ^= (0x80000000u | (unsigned)((int)u >> 31));
  return (u & 0xFFFFF000u) | (unsigned)idx;
}

// sorted-desc 8-slot insert via max/min bubble-through (16 VALU, no branches)
DEV void ins8(unsigned (&s)[8], unsigned p) {
#pragma unroll
  for (int j = 0; j < 8; ++j) {
    unsigned mx = s[j] > p ? s[j] : p;
    unsigned mn = s[j] > p ? p : s[j];
    s[j] = mx;
    p = mn;
  }
}

// ---- fused NCHW->NHWC transpose + weights prep (conv W packed bf16 tiled:
// rows = out-channel n, k = tap*64+ci, layout [n>>3][kc(18)][seg][n&7][e])
__global__ __launch_bounds__(256) void k_prep(
    const float* __restrict__ x, float* __restrict__ xt,
    const float* __restrict__ w1, const float* __restrict__ w2,
    const float* __restrict__ wt1, const float* __restrict__ bt1,
    const float* __restrict__ wt2, const float* __restrict__ bt2,
    ushort_t* __restrict__ Wb1t, ushort_t* __restrict__ Wb2t,
    float* __restrict__ Wcat, float* __restrict__ beff) {
  int t = threadIdx.x;
  if (blockIdx.x < 256) {
    __shared__ float tile[64][65];
    int wg = blockIdx.x;
    int b = wg >> 6, pt = wg & 63;
    int lane = t & 63, grp = t >> 6;
    const float* xb = x + ((size_t)b * 64) * 4096 + pt * 64;
#pragma unroll
    for (int j = 0; j < 16; ++j) {
      int c = j * 4 + grp;
      tile[c][lane] = xb[(size_t)c * 4096 + lane];
    }
    __syncthreads();
    float* xtb = xt + ((size_t)b * 4096 + (size_t)pt * 64) * 64;
#pragma unroll
    for (int j = 0; j < 16; ++j) {
      int p = j * 4 + grp;
      xtb[p * 64 + lane] = tile[lane][p];
    }
    return;
  }
  int id = (blockIdx.x - 256) * 256 + t;
  if (id < 36864) {
    int n = id & 63, d = id >> 6;
    __hip_bfloat16 h = __float2bfloat16(w1[(n * 64 + (d & 63)) * 9 + (d >> 6)]);
    Wb1t[(n >> 3) * 4608 + (d >> 5) * 256 + ((d >> 3) & 3) * 64 + (n & 7) * 8 + (d & 7)] =
        *(ushort_t*)&h;
  } else if (id < 73728) {
    int rel = id - 36864;
    int n = rel & 63, d = rel >> 6;
    __hip_bfloat16 h = __float2bfloat16(w2[(n * 64 + (d & 63)) * 9 + (d >> 6)]);
    Wb2t[(n >> 3) * 4608 + (d >> 5) * 256 + ((d >> 3) & 3) * 64 + (n & 7) * 8 + (d & 7)] =
        *(ushort_t*)&h;
  } else if (id < 81920) {
    int rel = id - 73728;
    int co = rel & 63, k = rel >> 6;  // k in [0,128)
    Wcat[k * 64 + co] = wt2[co * 192 + k];
  } else if (id < 98304) {
    int rel = id - 81920;
    int co = rel & 63, j = rel >> 6;  // j in [0,256)
    float s = 0.f;
    for (int ct = 0; ct < 64; ++ct) s += wt2[co * 192 + 128 + ct] * wt1[ct * 256 + j];
    Wcat[(128 + j) * 64 + co] = s;
  } else if (id < 98368) {
    int co = id - 98304;
    float s = bt2[co];
    for (int ct = 0; ct < 64; ++ct) s += wt2[co * 192 + 128 + ct] * bt1[ct];
    beff[co] = s;
  }
}

// ------------------- unfold (reflect) -> NORMALIZED fp8-e4m3 tiled + f64 norms
__global__ __launch_bounds__(512) void k_unfold(const float* __restrict__ xt,
                                                uint8_t* __restrict__ Xq,
                                                double* __restrict__ dinv) {
  __shared__ uint8_t U[4608];
  int rbg = blockIdx.x;           // 0..2047
  int b = rbg >> 9, rb = rbg & 511;
  int t = threadIdx.x;
  int p = t >> 6, lane = t & 63;
  int l = rb * 8 + p;
  int y = l >> 6, xq = l & 63;
  const float* xb = xt + ((size_t)b * 4096) * 64;
  float v[9];
  double s = 0.0;
#pragma unroll
  for (int tap = 0; tap < 9; ++tap) {
    int kh = tap / 3, kw = tap % 3;
    int gy = refl(y + kh - 1), gx = refl(xq + kw - 1);
    v[tap] = xb[(gy * 64 + gx) * 64 + lane];
    s += (double)v[tap] * (double)v[tap];
  }
#pragma unroll
  for (int off = 32; off; off >>= 1) s += __shfl_xor(s, off, 64);
  double n = sqrt(s);
  if (n < 1e-12) n = 1e-12;
  if (lane == 0) dinv[b * 4096 + l] = 1.0 / n;
  float inv = (float)(1.0 / n);
#pragma unroll
  for (int tap = 0; tap < 9; ++tap) {
    __hip_fp8_e4m3 h(v[tap] * inv);
    U[tap * 512 + (lane >> 4) * 128 + p * 16 + (lane & 15)] = h.__x;
  }
  __syncthreads();
  uint8_t* g = Xq + (size_t)rbg * 4608;
  if (t < 288) *(uint4*)&g[t * 16] = *(const uint4*)&U[t * 16];
}

// ---- 3x3 conv as implicit-im2col bf16 MFMA GEMM: block = 1 image row
// (64 px) x 64 outch; A staged f32->bf16 into gram's tiled slot order,
// W pre-packed (k_prep) in identical layout; 18 kc-chunks double-buffered.
__global__ __launch_bounds__(256) void k_cgemm(const float* __restrict__ in_t,
                                               const ushort_t* __restrict__ Wt,
                                               const float* __restrict__ bias,
                                               float* __restrict__ out_t,
                                               int do_relu) {
  __shared__ __align__(16) ushort_t Ab[2][2048];
  __shared__ __align__(16) ushort_t Bb[2][2048];
  int t = threadIdx.x;
  int w = t >> 6, lane = t & 63, rr = lane & 31, half = lane >> 5;
  int mi = w >> 1, ni = w & 1;
  int bid = blockIdx.x;
  int b = bid >> 6, y = bid & 63;
  const float* xrow = in_t + ((size_t)b * 4096) * 64;
  int sr = t >> 2, sq = t & 3;   // staging: row(px-x) 0..63, channel quad

  float bz = bias[ni * 32 + rr];
  f32x16 acc;
#pragma unroll
  for (int q = 0; q < 16; ++q) acc[q] = bz;

  // stage kc into buf: A (f32->bf16 cvt) + B (gload)
#define STAGE_CONV(kc_, buf_)                                                   \
  {                                                                             \
    int tap = (kc_) >> 1, ch = ((kc_) & 1) * 32 + sq * 8;                       \
    int kh = tap / 3, kw = tap % 3;                                             \
    int gy = y + kh - 1, gx = sr + kw - 1;                                      \
    ushort_t tmp[8];                                                            \
    if (gy >= 0 && gy < 64 && gx >= 0 && gx < 64) {                             \
      const float* src = xrow + ((size_t)(gy * 64 + gx)) * 64 + ch;             \
      float4 v0 = *(const float4*)src;                                          \
      float4 v1 = *(const float4*)(src + 4);                                    \
      float vv[8] = {v0.x, v0.y, v0.z, v0.w, v1.x, v1.y, v1.z, v1.w};           \
      _Pragma("unroll") for (int j = 0; j < 8; ++j) {                           \
        __hip_bfloat16 h = __float2bfloat16(vv[j]);                             \
        tmp[j] = *(ushort_t*)&h;                                                \
      }                                                                         \
    } else {                                                                    \
      _Pragma("unroll") for (int j = 0; j < 8; ++j) tmp[j] = 0;                 \
    }                                                                           \
    *(uint4*)&Ab[buf_][(sr >> 3) * 256 + sq * 64 + (sr & 7) * 8] = *(uint4*)tmp;\
    gload_lds16(Wt + (size_t)(t >> 5) * 4608 + (kc_) * 256 + (t & 31) * 8,      \
                &Bb[buf_][t * 8]);                                              \
  }

  STAGE_CONV(0, 0)
#pragma unroll 2
  for (int kc = 0; kc < 18; ++kc) {
    __syncthreads();
    if (kc < 17) STAGE_CONV(kc + 1, (kc + 1) & 1)
    const ushort_t* tA = Ab[kc & 1];
    const ushort_t* tB = Bb[kc & 1];
#pragma unroll
    for (int ks = 0; ks < 2; ++ks) {
      int seg8 = (ks * 2 + half) * 8 + (rr & 7);
      short8 af = *(const short8*)&tA[(mi * 4 + (rr >> 3)) * 256 + seg8 * 8];
      short8 bf = *(const short8*)&tB[(ni * 4 + (rr >> 3)) * 256 + seg8 * 8];
      acc = __builtin_amdgcn_mfma_f32_32x32x16_bf16(af, bf, acc, 0, 0, 0);
    }
  }
#undef STAGE_CONV
  // epilogue: C[m][n], col = lane&31, row = (reg&3)+8*(reg>>2)+4*half
  float* orow = out_t + ((size_t)b * 4096 + y * 64) * 64;
  int n = ni * 32 + rr;
#pragma unroll
  for (int reg = 0; reg < 16; ++reg) {
    int m = mi * 32 + (reg & 3) + 8 * (reg >> 2) + 4 * half;
    float vv = acc[reg];
    if (do_relu) vv = fmaxf(vv, 0.f);
    orow[m * 64 + n] = vv;
  }
}

// -------- fp8 Gram (pre-normalized qn => acc IS R), 256-row tiles, 64 r/wave
// (R13-proven version, reverted from R14's flat pipeline)
__global__ __launch_bounds__(256, 4) void k_gram(const uint8_t* __restrict__ Xq,
                                                 int* __restrict__ pidx) {
  __shared__ __align__(16) char lds[40960];
  uint8_t* sAb = (uint8_t*)lds;             // 2 bufs x 16KB
  uint8_t* sBb = (uint8_t*)(lds + 32768);   // 2 bufs x 4KB

  int wg = blockIdx.x;
  int u = wg & 7, v = wg >> 3;
  int bs = u + 8 * (v & 1);        // (b,sp) group: 2 per XCD
  int b = bs >> 2, sp = bs & 3;
  int cb = v >> 1;                 // 0..63
  int colbase = cb * 64;
  int t = threadIdx.x;
  int w = t >> 6, lane = t & 63;
  int rr = lane & 31, half = lane >> 5;

  const uint8_t* Xb = Xq + (size_t)b * 512 * 4608;
  const uint8_t* XB = Xb + (size_t)(cb * 8) * 4608;

  unsigned list[8];
#pragma unroll
  for (int j = 0; j < 8; ++j) list[j] = 0u;

#pragma unroll 1
  for (int mt = 0; mt < 4; ++mt) {
    int rowbase = sp * 1024 + mt * 256;
    __syncthreads();   // prev mt staging consume done, bufs free
    const uint8_t* XA = Xb + (size_t)(sp * 128 + mt * 32) * 4608;
    f32x16 acc[2][2];
#pragma unroll
    for (int im = 0; im < 2; ++im)
#pragma unroll
      for (int il = 0; il < 2; ++il)
#pragma unroll
        for (int q = 0; q < 16; ++q) acc[im][il][q] = 0.f;
    // prologue: stage kc=0 (A: 1024 slots, B: 256 slots, 16B each)
    {
#pragma unroll
      for (int j = 0; j < 4; ++j) {
        int s = j * 256 + t;
        gload_lds16(XA + (size_t)(s >> 5) * 4608 + (s & 31) * 16, sAb + s * 16);
      }
      gload_lds16(XB + (size_t)(t >> 5) * 4608 + (t & 31) * 16, sBb + t * 16);
    }
#pragma unroll 1
    for (int kc = 0; kc < 9; ++kc) {
      __syncthreads();
      if (kc < 8) {
        int buf = (kc + 1) & 1;
        int ko = (kc + 1) * 512;
#pragma unroll
        for (int j = 0; j < 4; ++j) {
          int s = j * 256 + t;
          gload_lds16(XA + (size_t)(s >> 5) * 4608 + ko + (s & 31) * 16,
                      sAb + buf * 16384 + s * 16);
        }
        gload_lds16(XB + (size_t)(t >> 5) * 4608 + ko + (t & 31) * 16,
                    sBb + buf * 4096 + t * 16);
      }
      const uint8_t* tA = sAb + (kc & 1) * 16384;
      const uint8_t* tB = sBb + (kc & 1) * 4096;
#pragma unroll
      for (int j = 0; j < 4; ++j) {
        int so = (j * 8 + (rr & 7)) * 16 + half * 8;
        long a0 = *(const long*)&tA[((w * 8 + (rr >> 3)) * 32) * 16 + so];
        long a1 = *(const long*)&tA[((w * 8 + 4 + (rr >> 3)) * 32) * 16 + so];
        long b0 = *(const long*)&tB[(((rr >> 3)) * 32) * 16 + so];
        long b1 = *(const long*)&tB[((4 + (rr >> 3)) * 32) * 16 + so];
        acc[0][0] = __builtin_amdgcn_mfma_f32_32x32x16_fp8_fp8(a0, b0, acc[0][0], 0, 0, 0);
        acc[0][1] = __builtin_amdgcn_mfma_f32_32x32x16_fp8_fp8(a0, b1, acc[0][1], 0, 0, 0);
        acc[1][0] = __builtin_amdgcn_mfma_f32_32x32x16_fp8_fp8(a1, b0, acc[1][0], 0, 0, 0);
        acc[1][1] = __builtin_amdgcn_mfma_f32_32x32x16_fp8_fp8(a1, b1, acc[1][1], 0, 0, 0);
      }
    }
    // packed top-8 update: 64 candidates/lane (own + partner columns)
    int rowb = rowbase + w * 64;
#pragma unroll
    for (int im = 0; im < 2; ++im) {
#pragma unroll
      for (int reg = 0; reg < 16; ++reg) {
        float a0 = acc[im][0][reg], a1 = acc[im][1][reg];
        float vo = half ? a1 : a0;   // own column (il == half)
        float vs = half ? a0 : a1;   // partner column
        float vr = __shfl_xor(vs, 32, 64);
        int rbase = rowb + im * 32 + (reg & 3) + 8 * (reg >> 2);
        ins8(list, packval(vo, rbase + 4 * half));
        ins8(list, packval(vr, rbase + 4 * (1 - half)));
      }
    }
  }
  // merge 4 wave-lists -> top-8 per column
  __syncthreads();
  unsigned* M = (unsigned*)lds;
#pragma unroll
  for (int j = 0; j < 8; ++j) M[lane * 33 + w * 8 + j] = list[j];
  __syncthreads();
  if (t < 64) {
    unsigned bl[8];
#pragma unroll
    for (int j = 0; j < 8; ++j) bl[j] = 0u;
#pragma unroll 1
    for (int i = 0; i < 32; ++i) ins8(bl, M[t * 33 + i]);
    size_t base = (((size_t)b * 4 + sp) * 4096 + colbase + t) * 8;
#pragma unroll
    for (int j = 0; j < 8; ++j) pidx[base + j] = (int)bl[j];
  }
}

// ---- fp8-top-8 tournament, then exact f64 refine (4 candidates/iteration
// via 16-lane quarter-groups; lane covers 4 channels with float4 gathers)
__global__ __launch_bounds__(256) void k_refine(const float* __restrict__ xt,
                                                const double* __restrict__ dinv,
                                                const int* __restrict__ pidx,
                                                float* __restrict__ Sval,
                                                int* __restrict__ Sidx) {
  int w = threadIdx.x >> 6, lane = threadIdx.x & 63;
  int gl = blockIdx.x * 4 + w;
  int b = gl >> 12, l = gl & 4095;
  int y = l >> 6, xq = l & 63;
  const float* xb = xt + ((size_t)b * 4096) * 64;
  unsigned cp = 0u;
  if (lane < 32) {
    int sp = lane >> 3, j = lane & 7;
    cp = (unsigned)pidx[(((size_t)b * 4 + sp) * 4096 + l) * 8 + j];
  }
  // tournament: top-8 by packed value (indices unique -> values unique)
  int wm[8];
#pragma unroll
  for (int r = 0; r < 8; ++r) {
    unsigned v = cp;
#pragma unroll
    for (int off = 32; off; off >>= 1) {
      unsigned ov = __shfl_xor(v, off, 64);
      v = ov > v ? ov : v;
    }
    wm[r] = (int)(v & 4095u);
    if (cp == v) cp = 0u;
  }
  // own-patch channels for this lane's quarter-group: ch = (lane&15)*4
  int ch4 = (lane & 15) * 4;
  float4 xl4[9];
#pragma unroll
  for (int tap = 0; tap < 9; ++tap) {
    int kh = tap / 3, kw = tap % 3;
    xl4[tap] = *(const float4*)&xb[(refl(y + kh - 1) * 64 + refl(xq + kw - 1)) * 64 + ch4];
  }
  double il = dinv[b * 4096 + l];
  double rv = -1e30;
  int ridx = 0x7fffffff;
#pragma unroll
  for (int it = 0; it < 2; ++it) {
    int m = wm[it * 4 + (lane >> 4)];
    int my = m >> 6, mx = m & 63;
    double d = 0.0;
#pragma unroll
    for (int tap = 0; tap < 9; ++tap) {
      int kh = tap / 3, kw = tap % 3;
      float4 gv = *(const float4*)&xb[(refl(my + kh - 1) * 64 + refl(mx + kw - 1)) * 64 + ch4];
      d += (double)xl4[tap].x * (double)gv.x + (double)xl4[tap].y * (double)gv.y +
           (double)xl4[tap].z * (double)gv.z + (double)xl4[tap].w * (double)gv.w;
    }
#pragma unroll
    for (int off = 1; off < 16; off <<= 1) d += __shfl_xor(d, off, 64);
    double R = d * il * dinv[b * 4096 + m];
    // lane r = it*4+g receives R of group g (source lane g*16)
    double Rsrc = __shfl(R, (lane & 3) * 16, 64);
    int msrc = __shfl(m, (lane & 3) * 16, 64);
    if ((lane >> 2) == it && lane < 8) { rv = Rsrc; ridx = msrc; }
  }
  // exact top-5 (rank 0 is self); emit ranks 1..4; ties -> lower index first
#pragma unroll
  for (int r = 0; r < 5; ++r) {
    double v = rv;
    int i = ridx;
#pragma unroll
    for (int off = 32; off; off >>= 1) {
      double ov = __shfl_xor(v, off, 64);
      int oi = __shfl_xor(i, off, 64);
      if (ov > v || (ov == v && oi < i)) { v = ov; i = oi; }
    }
    if (r >= 1 && lane == 0) {
      Sval[((size_t)b * 5 + r) * 4096 + l] = (float)v;
      Sidx[((size_t)b * 5 + r) * 4096 + l] = i;
    }
    if (rv == v && ridx == i) rv = -1e30;
  }
}

// ------------------------- fused fold/scale + composed 1x1 convs -> y (NCHW)
__global__ __launch_bounds__(256, 4) void k_out(const float* __restrict__ xt,
                                                const float* __restrict__ feat,
                                                const float* __restrict__ Sval,
                                                const int* __restrict__ Sidx,
                                                const float* __restrict__ Wcat,
                                                const float* __restrict__ beff,
                                                float* __restrict__ out) {
  __shared__ float X[16 * 388];   // stride 388 (16B aligned rows)
  __shared__ int SI[3 * 18 * 4];  // halo match indices, 0x7fffffff = outside
  __shared__ float SV[16 * 4];
  int t = threadIdx.x;
  int w = t >> 6, lane = t & 63;
  int p0 = blockIdx.x * 16;
  int b = p0 >> 12, pl = p0 & 4095;
  int y0 = pl >> 6, x0 = pl & 63;
  // ---- stage A: prefetch
  if (t < 216) {
    int r = t / 72, rem = t % 72;
    int c = rem >> 2, i = (rem & 3) + 1;
    int qy = y0 - 1 + r, qx = x0 - 1 + c;
    int m = 0x7fffffff;
    if (qy >= 0 && qy < 64 && qx >= 0 && qx < 64)
      m = Sidx[((size_t)b * 5 + i) * 4096 + qy * 64 + qx] & 4095;
    SI[(r * 18 + c) * 4 + (i - 1)] = m;
  }
  if (t < 64) {
    int px = t >> 2, i = (t & 3) + 1;
    SV[px * 4 + (i - 1)] = Sval[((size_t)b * 5 + i) * 4096 + pl + px];
  }
#pragma unroll
  for (int jj = 0; jj < 4; ++jj) {
    int px = w * 4 + jj;
    X[px * 388 + lane] = feat[((size_t)b * 4096 + pl + px) * 64 + lane];
    X[px * 388 + 64 + lane] = xt[((size_t)b * 4096 + pl + px) * 64 + lane];
  }
  __syncthreads();
  // ---- stage B: gathers. 64 (px,i) pairs; wave w owns pairs [16w,16w+16)
  const float* xb = xt + ((size_t)b * 4096) * 64;
#pragma unroll 4
  for (int k = 0; k < 16; ++k) {
    int pr = w * 16 + k;
    int px = pr >> 2, i = pr & 3;  // i rank-1 in 0..3
    float a = 0.f;
#pragma unroll
    for (int tap = 0; tap < 9; ++tap) {
      int kh = tap / 3, kw = tap % 3;
      int m = SI[((2 - kh) * 18 + px + 2 - kw) * 4 + i];
      if (m != 0x7fffffff) {
        int gy = refl((m >> 6) + kh - 1), gx = refl((m & 63) + kw - 1);
        a += xb[(gy * 64 + gx) * 64 + lane];
      }
    }
    X[px * 388 + 128 + i * 64 + lane] = a * SV[px * 4 + i] * (1.f / 9.f);
  }
  __syncthreads();
  // ---- stage C: matvec 384 -> 64, 4 outputs/thread, float4 X reads
  int px = t & 15, cog = t >> 4;
  float4 acc = *(const float4*)&beff[cog * 4];
#pragma unroll 2
  for (int k = 0; k < 384; k += 4) {
    float4 xv = *(const float4*)&X[px * 388 + k];
    float4 w0 = *(const float4*)&Wcat[(k + 0) * 64 + cog * 4];
    float4 w1 = *(const float4*)&Wcat[(k + 1) * 64 + cog * 4];
    float4 w2 = *(const float4*)&Wcat[(k + 2) * 64 + cog * 4];
    float4 w3 = *(const float4*)&Wcat[(k + 3) * 64 + cog * 4];
    acc.x += w0.x * xv.x + w1.x * xv.y + w2.x * xv.z + w3.x * xv.w;
    acc.y += w0.y * xv.x + w1.y * xv.y + w2.y * xv.z + w3.y * xv.w;
    acc.z += w0.z * xv.x + w1.z * xv.y + w2.z * xv.z + w3.z * xv.w;
    acc.w += w0.w * xv.x + w1.w * xv.y + w2.w * xv.z + w3.w * xv.w;
  }
  size_t ob = ((size_t)b * 64 + cog * 4) * 4096 + pl + px;
  out[ob] = acc.x;
  out[ob + 4096] = acc.y;
  out[ob + 8192] = acc.z;
  out[ob + 12288] = acc.w;
}

// ---------------------------------------------------------------------- launch
extern "C" void kernel_launch(void* const* d_in, const int* in_sizes, int n_in,
                              void* d_out, int out_size, void* d_ws, size_t ws_size,
                              hipStream_t stream) {
  const float* x = (const float*)d_in[0];
  const float* w1 = (const float*)d_in[1];
  const float* b1 = (const float*)d_in[2];
  const float* w2 = (const float*)d_in[3];
  const float* b2 = (const float*)d_in[4];
  const float* wt1 = (const float*)d_in[5];
  const float* bt1 = (const float*)d_in[6];
  const float* wt2 = (const float*)d_in[7];
  const float* bt2 = (const float*)d_in[8];

  char* ws = (char*)d_ws;
  float* x_t = (float*)(ws + 0);                       //  4 MB NHWC x
  float* y1 = (float*)(ws + 4194304);                  //  4 MB relu(conv1)
  float* feat = (float*)(ws + 8388608);                //  4 MB conv2
  uint8_t* Xq = (uint8_t*)(ws + 12582912);             //  9.4 MB fp8 qn unfold
  double* dinv = (double*)(ws + 31457280);             // 128 KB f64 1/norm
  int* pidx = (int*)(ws + 31653888);                   //  2 MB
  float* Sval = (float*)(ws + 33751040);               // 320 KB
  int* Sidx = (int*)(ws + 34078720);                   // 320 KB
  ushort_t* Wb1t = (ushort_t*)(ws + 34406400);         // 72 KB bf16 tiled W1
  ushort_t* Wb2t = (ushort_t*)(ws + 34553856);         // 72 KB bf16 tiled W2
  float* Wcat = (float*)(ws + 34701312);               //  96 KB
  float* beff = (float*)(ws + 34799616);               // 256 B
  float* out = (float*)d_out;

  k_prep<<<dim3(641), dim3(256), 0, stream>>>(x, x_t, w1, w2, wt1, bt1, wt2, bt2,
                                              Wb1t, Wb2t, Wcat, beff);
  k_unfold<<<dim3(2048), dim3(512), 0, stream>>>(x_t, Xq, dinv);
  k_cgemm<<<dim3(256), dim3(256), 0, stream>>>(x_t, Wb1t, b1, y1, 1);
  k_cgemm<<<dim3(256), dim3(256), 0, stream>>>(y1, Wb2t, b2, feat, 0);
  k_gram<<<dim3(1024), dim3(256), 0, stream>>>(Xq, pidx);
  k_refine<<<dim3(4096), dim3(256), 0, stream>>>(x_t, dinv, pidx, Sval, Sidx);
  k_out<<<dim3(1024), dim3(256), 0, stream>>>(x_t, feat, Sval, Sidx, Wcat, beff, out);
}

// Round 16
// 313.267 us; speedup vs baseline: 1.2671x; 1.0255x over previous
//
#include <hip/hip_runtime.h>
#include <hip/hip_bf16.h>
#include <hip/hip_fp8.h>
#include <stdint.h>

typedef unsigned short ushort_t;
typedef __attribute__((ext_vector_type(8))) short short8;
typedef __attribute__((ext_vector_type(16))) float f32x16;
typedef __attribute__((ext_vector_type(8))) int i32x8;
typedef __attribute__((ext_vector_type(4))) int i32x4;

#define DEV __device__ __forceinline__

DEV int refl(int j) { return j < 0 ? -j : (j > 63 ? 126 - j : j); }

DEV void gload_lds16(const void* g, void* l) {
  __builtin_amdgcn_global_load_lds(
      (const __attribute__((address_space(1))) unsigned int*)g,
      (__attribute__((address_space(3))) unsigned int*)l, 16, 0, 0);
}

// packed candidate: monotone top-20 bits of float | 12-bit row index
DEV unsigned packval(float v, int idx) {
  unsigned u = __float_as_uint(v);
  u ^= (0x80000000u | (unsigned)((int)u >> 31));
  return (u & 0xFFFFF000u) | (unsigned)idx;
}

// sorted-desc 8-slot insert via max/min bubble-through (16 VALU, no branches)
DEV void ins8(unsigned (&s)[8], unsigned p) {
#pragma unroll
  for (int j = 0; j < 8; ++j) {
    unsigned mx = s[j] > p ? s[j] : p;
    unsigned mn = s[j] > p ? p : s[j];
    s[j] = mx;
    p = mn;
  }
}

// two 16B LDS granules -> v8i32 MFMA fragment (K=64 fp8 bytes per lane-row)
DEV i32x8 ldfrag(const uint8_t* p0, const uint8_t* p1) {
  i32x4 lo = *(const i32x4*)p0;
  i32x4 hi = *(const i32x4*)p1;
  i32x8 r;
  r[0] = lo[0]; r[1] = lo[1]; r[2] = lo[2]; r[3] = lo[3];
  r[4] = hi[0]; r[5] = hi[1]; r[6] = hi[2]; r[7] = hi[3];
  return r;
}

// ---- fused NCHW->NHWC transpose + weights prep (conv W packed bf16 tiled:
// rows = out-channel n, k = tap*64+ci, layout [n>>3][kc(18)][seg][n&7][e])
__global__ __launch_bounds__(256) void k_prep(
    const float* __restrict__ x, float* __restrict__ xt,
    const float* __restrict__ w1, const float* __restrict__ w2,
    const float* __restrict__ wt1, const float* __restrict__ bt1,
    const float* __restrict__ wt2, const float* __restrict__ bt2,
    ushort_t* __restrict__ Wb1t, ushort_t* __restrict__ Wb2t,
    float* __restrict__ Wcat, float* __restrict__ beff) {
  int t = threadIdx.x;
  if (blockIdx.x < 256) {
    __shared__ float tile[64][65];
    int wg = blockIdx.x;
    int b = wg >> 6, pt = wg & 63;
    int lane = t & 63, grp = t >> 6;
    const float* xb = x + ((size_t)b * 64) * 4096 + pt * 64;
#pragma unroll
    for (int j = 0; j < 16; ++j) {
      int c = j * 4 + grp;
      tile[c][lane] = xb[(size_t)c * 4096 + lane];
    }
    __syncthreads();
    float* xtb = xt + ((size_t)b * 4096 + (size_t)pt * 64) * 64;
#pragma unroll
    for (int j = 0; j < 16; ++j) {
      int p = j * 4 + grp;
      xtb[p * 64 + lane] = tile[lane][p];
    }
    return;
  }
  int id = (blockIdx.x - 256) * 256 + t;
  if (id < 36864) {
    int n = id & 63, d = id >> 6;
    __hip_bfloat16 h = __float2bfloat16(w1[(n * 64 + (d & 63)) * 9 + (d >> 6)]);
    Wb1t[(n >> 3) * 4608 + (d >> 5) * 256 + ((d >> 3) & 3) * 64 + (n & 7) * 8 + (d & 7)] =
        *(ushort_t*)&h;
  } else if (id < 73728) {
    int rel = id - 36864;
    int n = rel & 63, d = rel >> 6;
    __hip_bfloat16 h = __float2bfloat16(w2[(n * 64 + (d & 63)) * 9 + (d >> 6)]);
    Wb2t[(n >> 3) * 4608 + (d >> 5) * 256 + ((d >> 3) & 3) * 64 + (n & 7) * 8 + (d & 7)] =
        *(ushort_t*)&h;
  } else if (id < 81920) {
    int rel = id - 73728;
    int co = rel & 63, k = rel >> 6;  // k in [0,128)
    Wcat[k * 64 + co] = wt2[co * 192 + k];
  } else if (id < 98304) {
    int rel = id - 81920;
    int co = rel & 63, j = rel >> 6;  // j in [0,256)
    float s = 0.f;
    for (int ct = 0; ct < 64; ++ct) s += wt2[co * 192 + 128 + ct] * wt1[ct * 256 + j];
    Wcat[(128 + j) * 64 + co] = s;
  } else if (id < 98368) {
    int co = id - 98304;
    float s = bt2[co];
    for (int ct = 0; ct < 64; ++ct) s += wt2[co * 192 + 128 + ct] * bt1[ct];
    beff[co] = s;
  }
}

// ------------------- unfold (reflect) -> NORMALIZED fp8-e4m3 tiled + f64 norms
__global__ __launch_bounds__(512) void k_unfold(const float* __restrict__ xt,
                                                uint8_t* __restrict__ Xq,
                                                double* __restrict__ dinv) {
  __shared__ uint8_t U[4608];
  int rbg = blockIdx.x;           // 0..2047
  int b = rbg >> 9, rb = rbg & 511;
  int t = threadIdx.x;
  int p = t >> 6, lane = t & 63;
  int l = rb * 8 + p;
  int y = l >> 6, xq = l & 63;
  const float* xb = xt + ((size_t)b * 4096) * 64;
  float v[9];
  double s = 0.0;
#pragma unroll
  for (int tap = 0; tap < 9; ++tap) {
    int kh = tap / 3, kw = tap % 3;
    int gy = refl(y + kh - 1), gx = refl(xq + kw - 1);
    v[tap] = xb[(gy * 64 + gx) * 64 + lane];
    s += (double)v[tap] * (double)v[tap];
  }
#pragma unroll
  for (int off = 32; off; off >>= 1) s += __shfl_xor(s, off, 64);
  double n = sqrt(s);
  if (n < 1e-12) n = 1e-12;
  if (lane == 0) dinv[b * 4096 + l] = 1.0 / n;
  float inv = (float)(1.0 / n);
#pragma unroll
  for (int tap = 0; tap < 9; ++tap) {
    __hip_fp8_e4m3 h(v[tap] * inv);
    U[tap * 512 + (lane >> 4) * 128 + p * 16 + (lane & 15)] = h.__x;
  }
  __syncthreads();
  uint8_t* g = Xq + (size_t)rbg * 4608;
  if (t < 288) *(uint4*)&g[t * 16] = *(const uint4*)&U[t * 16];
}

// ---- 3x3 conv as implicit-im2col bf16 MFMA GEMM: block = 1 image row
// (64 px) x 64 outch; A staged f32->bf16 into gram's tiled slot order,
// W pre-packed (k_prep) in identical layout; 18 kc-chunks double-buffered.
__global__ __launch_bounds__(256) void k_cgemm(const float* __restrict__ in_t,
                                               const ushort_t* __restrict__ Wt,
                                               const float* __restrict__ bias,
                                               float* __restrict__ out_t,
                                               int do_relu) {
  __shared__ __align__(16) ushort_t Ab[2][2048];
  __shared__ __align__(16) ushort_t Bb[2][2048];
  int t = threadIdx.x;
  int w = t >> 6, lane = t & 63, rr = lane & 31, half = lane >> 5;
  int mi = w >> 1, ni = w & 1;
  int bid = blockIdx.x;
  int b = bid >> 6, y = bid & 63;
  const float* xrow = in_t + ((size_t)b * 4096) * 64;
  int sr = t >> 2, sq = t & 3;   // staging: row(px-x) 0..63, channel quad

  float bz = bias[ni * 32 + rr];
  f32x16 acc;
#pragma unroll
  for (int q = 0; q < 16; ++q) acc[q] = bz;

  // stage kc into buf: A (f32->bf16 cvt) + B (gload)
#define STAGE_CONV(kc_, buf_)                                                   \
  {                                                                             \
    int tap = (kc_) >> 1, ch = ((kc_) & 1) * 32 + sq * 8;                       \
    int kh = tap / 3, kw = tap % 3;                                             \
    int gy = y + kh - 1, gx = sr + kw - 1;                                      \
    ushort_t tmp[8];                                                            \
    if (gy >= 0 && gy < 64 && gx >= 0 && gx < 64) {                             \
      const float* src = xrow + ((size_t)(gy * 64 + gx)) * 64 + ch;             \
      float4 v0 = *(const float4*)src;                                          \
      float4 v1 = *(const float4*)(src + 4);                                    \
      float vv[8] = {v0.x, v0.y, v0.z, v0.w, v1.x, v1.y, v1.z, v1.w};           \
      _Pragma("unroll") for (int j = 0; j < 8; ++j) {                           \
        __hip_bfloat16 h = __float2bfloat16(vv[j]);                             \
        tmp[j] = *(ushort_t*)&h;                                                \
      }                                                                         \
    } else {                                                                    \
      _Pragma("unroll") for (int j = 0; j < 8; ++j) tmp[j] = 0;                 \
    }                                                                           \
    *(uint4*)&Ab[buf_][(sr >> 3) * 256 + sq * 64 + (sr & 7) * 8] = *(uint4*)tmp;\
    gload_lds16(Wt + (size_t)(t >> 5) * 4608 + (kc_) * 256 + (t & 31) * 8,      \
                &Bb[buf_][t * 8]);                                              \
  }

  STAGE_CONV(0, 0)
#pragma unroll 2
  for (int kc = 0; kc < 18; ++kc) {
    __syncthreads();
    if (kc < 17) STAGE_CONV(kc + 1, (kc + 1) & 1)
    const ushort_t* tA = Ab[kc & 1];
    const ushort_t* tB = Bb[kc & 1];
#pragma unroll
    for (int ks = 0; ks < 2; ++ks) {
      int seg8 = (ks * 2 + half) * 8 + (rr & 7);
      short8 af = *(const short8*)&tA[(mi * 4 + (rr >> 3)) * 256 + seg8 * 8];
      short8 bf = *(const short8*)&tB[(ni * 4 + (rr >> 3)) * 256 + seg8 * 8];
      acc = __builtin_amdgcn_mfma_f32_32x32x16_bf16(af, bf, acc, 0, 0, 0);
    }
  }
#undef STAGE_CONV
  // epilogue: C[m][n], col = lane&31, row = (reg&3)+8*(reg>>2)+4*half
  float* orow = out_t + ((size_t)b * 4096 + y * 64) * 64;
  int n = ni * 32 + rr;
#pragma unroll
  for (int reg = 0; reg < 16; ++reg) {
    int m = mi * 32 + (reg & 3) + 8 * (reg >> 2) + 4 * half;
    float vv = acc[reg];
    if (do_relu) vv = fmaxf(vv, 0.f);
    orow[m * 64 + n] = vv;
  }
}

// -------- fp8 Gram via MX-scaled MFMA 32x32x64 (unit scales), 256-row tiles
// Same staging/pipeline as R13; per kc: 8 ds_read_b128 + 4 scaled MFMAs
// (2x MFMA rate, K=64/instr). C/D layout shape-determined (same top-k path).
__global__ __launch_bounds__(256, 4) void k_gram(const uint8_t* __restrict__ Xq,
                                                 int* __restrict__ pidx) {
  __shared__ __align__(16) char lds[40960];
  uint8_t* sAb = (uint8_t*)lds;             // 2 bufs x 16KB
  uint8_t* sBb = (uint8_t*)(lds + 32768);   // 2 bufs x 4KB

  int wg = blockIdx.x;
  int u = wg & 7, v = wg >> 3;
  int bs = u + 8 * (v & 1);        // (b,sp) group: 2 per XCD
  int b = bs >> 2, sp = bs & 3;
  int cb = v >> 1;                 // 0..63
  int colbase = cb * 64;
  int t = threadIdx.x;
  int w = t >> 6, lane = t & 63;
  int rr = lane & 31, half = lane >> 5;
  int rb8 = rr >> 3, r8 = rr & 7;
  int so0 = (2 * half) * 8 + r8;   // granule idx within rb: seg*8 + r8
  int so1 = so0 + 8;               // next seg

  const uint8_t* Xb = Xq + (size_t)b * 512 * 4608;
  const uint8_t* XB = Xb + (size_t)(cb * 8) * 4608;

  unsigned list[8];
#pragma unroll
  for (int j = 0; j < 8; ++j) list[j] = 0u;

#pragma unroll 1
  for (int mt = 0; mt < 4; ++mt) {
    int rowbase = sp * 1024 + mt * 256;
    __syncthreads();   // prev mt staging consume done, bufs free
    const uint8_t* XA = Xb + (size_t)(sp * 128 + mt * 32) * 4608;
    f32x16 acc[2][2];
#pragma unroll
    for (int im = 0; im < 2; ++im)
#pragma unroll
      for (int il = 0; il < 2; ++il)
#pragma unroll
        for (int q = 0; q < 16; ++q) acc[im][il][q] = 0.f;
    // prologue: stage kc=0 (A: 1024 slots, B: 256 slots, 16B each)
    {
#pragma unroll
      for (int j = 0; j < 4; ++j) {
        int s = j * 256 + t;
        gload_lds16(XA + (size_t)(s >> 5) * 4608 + (s & 31) * 16, sAb + s * 16);
      }
      gload_lds16(XB + (size_t)(t >> 5) * 4608 + (t & 31) * 16, sBb + t * 16);
    }
#pragma unroll 1
    for (int kc = 0; kc < 9; ++kc) {
      __syncthreads();
      if (kc < 8) {
        int buf = (kc + 1) & 1;
        int ko = (kc + 1) * 512;
#pragma unroll
        for (int j = 0; j < 4; ++j) {
          int s = j * 256 + t;
          gload_lds16(XA + (size_t)(s >> 5) * 4608 + ko + (s & 31) * 16,
                      sAb + buf * 16384 + s * 16);
        }
        gload_lds16(XB + (size_t)(t >> 5) * 4608 + ko + (t & 31) * 16,
                    sBb + buf * 4096 + t * 16);
      }
      const uint8_t* tA = sAb + (kc & 1) * 16384;
      const uint8_t* tB = sBb + (kc & 1) * 4096;
      i32x8 af[2], bf[2];
#pragma unroll
      for (int im = 0; im < 2; ++im) {
        int rbA = w * 8 + im * 4 + rb8;
        af[im] = ldfrag(&tA[(rbA * 32 + so0) * 16], &tA[(rbA * 32 + so1) * 16]);
      }
#pragma unroll
      for (int il = 0; il < 2; ++il) {
        int rbB = il * 4 + rb8;
        bf[il] = ldfrag(&tB[(rbB * 32 + so0) * 16], &tB[(rbB * 32 + so1) * 16]);
      }
      acc[0][0] = __builtin_amdgcn_mfma_scale_f32_32x32x64_f8f6f4(
          af[0], bf[0], acc[0][0], 0, 0, 0, 0x7F7F7F7F, 0, 0x7F7F7F7F);
      acc[0][1] = __builtin_amdgcn_mfma_scale_f32_32x32x64_f8f6f4(
          af[0], bf[1], acc[0][1], 0, 0, 0, 0x7F7F7F7F, 0, 0x7F7F7F7F);
      acc[1][0] = __builtin_amdgcn_mfma_scale_f32_32x32x64_f8f6f4(
          af[1], bf[0], acc[1][0], 0, 0, 0, 0x7F7F7F7F, 0, 0x7F7F7F7F);
      acc[1][1] = __builtin_amdgcn_mfma_scale_f32_32x32x64_f8f6f4(
          af[1], bf[1], acc[1][1], 0, 0, 0, 0x7F7F7F7F, 0, 0x7F7F7F7F);
    }
    // packed top-8 update: 64 candidates/lane (own + partner columns)
    int rowb = rowbase + w * 64;
#pragma unroll
    for (int im = 0; im < 2; ++im) {
#pragma unroll
      for (int reg = 0; reg < 16; ++reg) {
        float a0 = acc[im][0][reg], a1 = acc[im][1][reg];
        float vo = half ? a1 : a0;   // own column (il == half)
        float vs = half ? a0 : a1;   // partner column
        float vr = __shfl_xor(vs, 32, 64);
        int rbase = rowb + im * 32 + (reg & 3) + 8 * (reg >> 2);
        ins8(list, packval(vo, rbase + 4 * half));
        ins8(list, packval(vr, rbase + 4 * (1 - half)));
      }
    }
  }
  // merge 4 wave-lists -> top-8 per column
  __syncthreads();
  unsigned* M = (unsigned*)lds;
#pragma unroll
  for (int j = 0; j < 8; ++j) M[lane * 33 + w * 8 + j] = list[j];
  __syncthreads();
  if (t < 64) {
    unsigned bl[8];
#pragma unroll
    for (int j = 0; j < 8; ++j) bl[j] = 0u;
#pragma unroll 1
    for (int i = 0; i < 32; ++i) ins8(bl, M[t * 33 + i]);
    size_t base = (((size_t)b * 4 + sp) * 4096 + colbase + t) * 8;
#pragma unroll
    for (int j = 0; j < 8; ++j) pidx[base + j] = (int)bl[j];
  }
}

// ---- fp8-top-8 tournament, then exact f64 refine (4 candidates/iteration
// via 16-lane quarter-groups; lane covers 4 channels with float4 gathers)
__global__ __launch_bounds__(256) void k_refine(const float* __restrict__ xt,
                                                const double* __restrict__ dinv,
                                                const int* __restrict__ pidx,
                                                float* __restrict__ Sval,
                                                int* __restrict__ Sidx) {
  int w = threadIdx.x >> 6, lane = threadIdx.x & 63;
  int gl = blockIdx.x * 4 + w;
  int b = gl >> 12, l = gl & 4095;
  int y = l >> 6, xq = l & 63;
  const float* xb = xt + ((size_t)b * 4096) * 64;
  unsigned cp = 0u;
  if (lane < 32) {
    int sp = lane >> 3, j = lane & 7;
    cp = (unsigned)pidx[(((size_t)b * 4 + sp) * 4096 + l) * 8 + j];
  }
  // tournament: top-8 by packed value (indices unique -> values unique)
  int wm[8];
#pragma unroll
  for (int r = 0; r < 8; ++r) {
    unsigned v = cp;
#pragma unroll
    for (int off = 32; off; off >>= 1) {
      unsigned ov = __shfl_xor(v, off, 64);
      v = ov > v ? ov : v;
    }
    wm[r] = (int)(v & 4095u);
    if (cp == v) cp = 0u;
  }
  // own-patch channels for this lane's quarter-group: ch = (lane&15)*4
  int ch4 = (lane & 15) * 4;
  float4 xl4[9];
#pragma unroll
  for (int tap = 0; tap < 9; ++tap) {
    int kh = tap / 3, kw = tap % 3;
    xl4[tap] = *(const float4*)&xb[(refl(y + kh - 1) * 64 + refl(xq + kw - 1)) * 64 + ch4];
  }
  double il = dinv[b * 4096 + l];
  double rv = -1e30;
  int ridx = 0x7fffffff;
#pragma unroll
  for (int it = 0; it < 2; ++it) {
    int m = wm[it * 4 + (lane >> 4)];
    int my = m >> 6, mx = m & 63;
    double d = 0.0;
#pragma unroll
    for (int tap = 0; tap < 9; ++tap) {
      int kh = tap / 3, kw = tap % 3;
      float4 gv = *(const float4*)&xb[(refl(my + kh - 1) * 64 + refl(mx + kw - 1)) * 64 + ch4];
      d += (double)xl4[tap].x * (double)gv.x + (double)xl4[tap].y * (double)gv.y +
           (double)xl4[tap].z * (double)gv.z + (double)xl4[tap].w * (double)gv.w;
    }
#pragma unroll
    for (int off = 1; off < 16; off <<= 1) d += __shfl_xor(d, off, 64);
    double R = d * il * dinv[b * 4096 + m];
    // lane r = it*4+g receives R of group g (source lane g*16)
    double Rsrc = __shfl(R, (lane & 3) * 16, 64);
    int msrc = __shfl(m, (lane & 3) * 16, 64);
    if ((lane >> 2) == it && lane < 8) { rv = Rsrc; ridx = msrc; }
  }
  // exact top-5 (rank 0 is self); emit ranks 1..4; ties -> lower index first
#pragma unroll
  for (int r = 0; r < 5; ++r) {
    double v = rv;
    int i = ridx;
#pragma unroll
    for (int off = 32; off; off >>= 1) {
      double ov = __shfl_xor(v, off, 64);
      int oi = __shfl_xor(i, off, 64);
      if (ov > v || (ov == v && oi < i)) { v = ov; i = oi; }
    }
    if (r >= 1 && lane == 0) {
      Sval[((size_t)b * 5 + r) * 4096 + l] = (float)v;
      Sidx[((size_t)b * 5 + r) * 4096 + l] = i;
    }
    if (rv == v && ridx == i) rv = -1e30;
  }
}

// ------------------------- fused fold/scale + composed 1x1 convs -> y (NCHW)
__global__ __launch_bounds__(256, 4) void k_out(const float* __restrict__ xt,
                                                const float* __restrict__ feat,
                                                const float* __restrict__ Sval,
                                                const int* __restrict__ Sidx,
                                                const float* __restrict__ Wcat,
                                                const float* __restrict__ beff,
                                                float* __restrict__ out) {
  __shared__ float X[16 * 388];   // stride 388 (16B aligned rows)
  __shared__ int SI[3 * 18 * 4];  // halo match indices, 0x7fffffff = outside
  __shared__ float SV[16 * 4];
  int t = threadIdx.x;
  int w = t >> 6, lane = t & 63;
  int p0 = blockIdx.x * 16;
  int b = p0 >> 12, pl = p0 & 4095;
  int y0 = pl >> 6, x0 = pl & 63;
  // ---- stage A: prefetch
  if (t < 216) {
    int r = t / 72, rem = t % 72;
    int c = rem >> 2, i = (rem & 3) + 1;
    int qy = y0 - 1 + r, qx = x0 - 1 + c;
    int m = 0x7fffffff;
    if (qy >= 0 && qy < 64 && qx >= 0 && qx < 64)
      m = Sidx[((size_t)b * 5 + i) * 4096 + qy * 64 + qx] & 4095;
    SI[(r * 18 + c) * 4 + (i - 1)] = m;
  }
  if (t < 64) {
    int px = t >> 2, i = (t & 3) + 1;
    SV[px * 4 + (i - 1)] = Sval[((size_t)b * 5 + i) * 4096 + pl + px];
  }
#pragma unroll
  for (int jj = 0; jj < 4; ++jj) {
    int px = w * 4 + jj;
    X[px * 388 + lane] = feat[((size_t)b * 4096 + pl + px) * 64 + lane];
    X[px * 388 + 64 + lane] = xt[((size_t)b * 4096 + pl + px) * 64 + lane];
  }
  __syncthreads();
  // ---- stage B: gathers. 64 (px,i) pairs; wave w owns pairs [16w,16w+16)
  const float* xb = xt + ((size_t)b * 4096) * 64;
#pragma unroll 4
  for (int k = 0; k < 16; ++k) {
    int pr = w * 16 + k;
    int px = pr >> 2, i = pr & 3;  // i rank-1 in 0..3
    float a = 0.f;
#pragma unroll
    for (int tap = 0; tap < 9; ++tap) {
      int kh = tap / 3, kw = tap % 3;
      int m = SI[((2 - kh) * 18 + px + 2 - kw) * 4 + i];
      if (m != 0x7fffffff) {
        int gy = refl((m >> 6) + kh - 1), gx = refl((m & 63) + kw - 1);
        a += xb[(gy * 64 + gx) * 64 + lane];
      }
    }
    X[px * 388 + 128 + i * 64 + lane] = a * SV[px * 4 + i] * (1.f / 9.f);
  }
  __syncthreads();
  // ---- stage C: matvec 384 -> 64, 4 outputs/thread, float4 X reads
  int px = t & 15, cog = t >> 4;
  float4 acc = *(const float4*)&beff[cog * 4];
#pragma unroll 2
  for (int k = 0; k < 384; k += 4) {
    float4 xv = *(const float4*)&X[px * 388 + k];
    float4 w0 = *(const float4*)&Wcat[(k + 0) * 64 + cog * 4];
    float4 w1 = *(const float4*)&Wcat[(k + 1) * 64 + cog * 4];
    float4 w2 = *(const float4*)&Wcat[(k + 2) * 64 + cog * 4];
    float4 w3 = *(const float4*)&Wcat[(k + 3) * 64 + cog * 4];
    acc.x += w0.x * xv.x + w1.x * xv.y + w2.x * xv.z + w3.x * xv.w;
    acc.y += w0.y * xv.x + w1.y * xv.y + w2.y * xv.z + w3.y * xv.w;
    acc.z += w0.z * xv.x + w1.z * xv.y + w2.z * xv.z + w3.z * xv.w;
    acc.w += w0.w * xv.x + w1.w * xv.y + w2.w * xv.z + w3.w * xv.w;
  }
  size_t ob = ((size_t)b * 64 + cog * 4) * 4096 + pl + px;
  out[ob] = acc.x;
  out[ob + 4096] = acc.y;
  out[ob + 8192] = acc.z;
  out[ob + 12288] = acc.w;
}

// ---------------------------------------------------------------------- launch
extern "C" void kernel_launch(void* const* d_in, const int* in_sizes, int n_in,
                              void* d_out, int out_size, void* d_ws, size_t ws_size,
                              hipStream_t stream) {
  const float* x = (const float*)d_in[0];
  const float* w1 = (const float*)d_in[1];
  const float* b1 = (const float*)d_in[2];
  const float* w2 = (const float*)d_in[3];
  const float* b2 = (const float*)d_in[4];
  const float* wt1 = (const float*)d_in[5];
  const float* bt1 = (const float*)d_in[6];
  const float* wt2 = (const float*)d_in[7];
  const float* bt2 = (const float*)d_in[8];

  char* ws = (char*)d_ws;
  float* x_t = (float*)(ws + 0);                       //  4 MB NHWC x
  float* y1 = (float*)(ws + 4194304);                  //  4 MB relu(conv1)
  float* feat = (float*)(ws + 8388608);                //  4 MB conv2
  uint8_t* Xq = (uint8_t*)(ws + 12582912);             //  9.4 MB fp8 qn unfold
  double* dinv = (double*)(ws + 31457280);             // 128 KB f64 1/norm
  int* pidx = (int*)(ws + 31653888);                   //  2 MB
  float* Sval = (float*)(ws + 33751040);               // 320 KB
  int* Sidx = (int*)(ws + 34078720);                   // 320 KB
  ushort_t* Wb1t = (ushort_t*)(ws + 34406400);         // 72 KB bf16 tiled W1
  ushort_t* Wb2t = (ushort_t*)(ws + 34553856);         // 72 KB bf16 tiled W2
  float* Wcat = (float*)(ws + 34701312);               //  96 KB
  float* beff = (float*)(ws + 34799616);               // 256 B
  float* out = (float*)d_out;

  k_prep<<<dim3(641), dim3(256), 0, stream>>>(x, x_t, w1, w2, wt1, bt1, wt2, bt2,
                                              Wb1t, Wb2t, Wcat, beff);
  k_unfold<<<dim3(2048), dim3(512), 0, stream>>>(x_t, Xq, dinv);
  k_cgemm<<<dim3(256), dim3(256), 0, stream>>>(x_t, Wb1t, b1, y1, 1);
  k_cgemm<<<dim3(256), dim3(256), 0, stream>>>(y1, Wb2t, b2, feat, 0);
  k_gram<<<dim3(1024), dim3(256), 0, stream>>>(Xq, pidx);
  k_refine<<<dim3(4096), dim3(256), 0, stream>>>(x_t, dinv, pidx, Sval, Sidx);
  k_out<<<dim3(1024), dim3(256), 0, stream>>>(x_t, feat, Sval, Sidx, Wcat, beff, out);
}

// Round 17
// 278.560 us; speedup vs baseline: 1.4250x; 1.1246x over previous
//
#include <hip/hip_runtime.h>
#include <hip/hip_bf16.h>
#include <hip/hip_fp8.h>
#include <stdint.h>

typedef unsigned short ushort_t;
typedef __attribute__((ext_vector_type(8))) short short8;
typedef __attribute__((ext_vector_type(16))) float f32x16;
typedef __attribute__((ext_vector_type(8))) int i32x8;
typedef __attribute__((ext_vector_type(4))) int i32x4;

#define DEV __device__ __forceinline__

DEV int refl(int j) { return j < 0 ? -j : (j > 63 ? 126 - j : j); }

DEV void gload_lds16(const void* g, void* l) {
  __builtin_amdgcn_global_load_lds(
      (const __attribute__((address_space(1))) unsigned int*)g,
      (__attribute__((address_space(3))) unsigned int*)l, 16, 0, 0);
}

// packed candidate: monotone top-20 bits of float | 12-bit row index
DEV unsigned packval(float v, int idx) {
  unsigned u = __float_as_uint(v);
  u ^= (0x80000000u | (unsigned)((int)u >> 31));
  return (u & 0xFFFFF000u) | (unsigned)idx;
}

// sorted-desc 8-slot insert via max/min bubble-through (16 VALU, no branches)
DEV void ins8(unsigned (&s)[8], unsigned p) {
#pragma unroll
  for (int j = 0; j < 8; ++j) {
    unsigned mx = s[j] > p ? s[j] : p;
    unsigned mn = s[j] > p ? p : s[j];
    s[j] = mx;
    p = mn;
  }
}

// two 16B LDS granules -> v8i32 MFMA fragment (K=64 fp8 bytes per lane-row)
DEV i32x8 ldfrag(const uint8_t* p0, const uint8_t* p1) {
  i32x4 lo = *(const i32x4*)p0;
  i32x4 hi = *(const i32x4*)p1;
  i32x8 r;
  r[0] = lo[0]; r[1] = lo[1]; r[2] = lo[2]; r[3] = lo[3];
  r[4] = hi[0]; r[5] = hi[1]; r[6] = hi[2]; r[7] = hi[3];
  return r;
}

// tiled bf16 offset (rb stride given): row r, depth d
DEV int toff(int r, int d, int rbstride) {
  return (r >> 3) * rbstride + (d >> 5) * 256 + ((d >> 3) & 3) * 64 + (r & 7) * 8 + (d & 7);
}

// ---- fused NCHW->NHWC transpose + weights prep (conv W + Wcat packed bf16
// tiled: rows = out-channel n, layout [n>>3][kc][seg][n&7][e])
__global__ __launch_bounds__(256) void k_prep(
    const float* __restrict__ x, float* __restrict__ xt,
    const float* __restrict__ w1, const float* __restrict__ w2,
    const float* __restrict__ wt1, const float* __restrict__ bt1,
    const float* __restrict__ wt2, const float* __restrict__ bt2,
    ushort_t* __restrict__ Wb1t, ushort_t* __restrict__ Wb2t,
    ushort_t* __restrict__ Wcatb, float* __restrict__ beff) {
  int t = threadIdx.x;
  if (blockIdx.x < 256) {
    __shared__ float tile[64][65];
    int wg = blockIdx.x;
    int b = wg >> 6, pt = wg & 63;
    int lane = t & 63, grp = t >> 6;
    const float* xb = x + ((size_t)b * 64) * 4096 + pt * 64;
#pragma unroll
    for (int j = 0; j < 16; ++j) {
      int c = j * 4 + grp;
      tile[c][lane] = xb[(size_t)c * 4096 + lane];
    }
    __syncthreads();
    float* xtb = xt + ((size_t)b * 4096 + (size_t)pt * 64) * 64;
#pragma unroll
    for (int j = 0; j < 16; ++j) {
      int p = j * 4 + grp;
      xtb[p * 64 + lane] = tile[lane][p];
    }
    return;
  }
  int id = (blockIdx.x - 256) * 256 + t;
  if (id < 36864) {
    int n = id & 63, d = id >> 6;
    __hip_bfloat16 h = __float2bfloat16(w1[(n * 64 + (d & 63)) * 9 + (d >> 6)]);
    Wb1t[toff(n, d, 4608)] = *(ushort_t*)&h;
  } else if (id < 73728) {
    int rel = id - 36864;
    int n = rel & 63, d = rel >> 6;
    __hip_bfloat16 h = __float2bfloat16(w2[(n * 64 + (d & 63)) * 9 + (d >> 6)]);
    Wb2t[toff(n, d, 4608)] = *(ushort_t*)&h;
  } else if (id < 98304) {
    int rel = id - 73728;
    int n = rel & 63, d = rel >> 6;  // d in [0,384)
    float s;
    if (d < 128) {
      s = wt2[n * 192 + d];
    } else {
      int j = d - 128;
      s = 0.f;
      for (int ct = 0; ct < 64; ++ct) s += wt2[n * 192 + 128 + ct] * wt1[ct * 256 + j];
    }
    __hip_bfloat16 h = __float2bfloat16(s);
    Wcatb[toff(n, d, 3072)] = *(ushort_t*)&h;
  } else if (id < 98368) {
    int co = id - 98304;
    float s = bt2[co];
    for (int ct = 0; ct < 64; ++ct) s += wt2[co * 192 + 128 + ct] * bt1[ct];
    beff[co] = s;
  }
}

// ------------------- unfold (reflect) -> NORMALIZED fp8-e4m3 tiled + f64 norms
__global__ __launch_bounds__(512) void k_unfold(const float* __restrict__ xt,
                                                uint8_t* __restrict__ Xq,
                                                double* __restrict__ dinv) {
  __shared__ uint8_t U[4608];
  int rbg = blockIdx.x;           // 0..2047
  int b = rbg >> 9, rb = rbg & 511;
  int t = threadIdx.x;
  int p = t >> 6, lane = t & 63;
  int l = rb * 8 + p;
  int y = l >> 6, xq = l & 63;
  const float* xb = xt + ((size_t)b * 4096) * 64;
  float v[9];
  double s = 0.0;
#pragma unroll
  for (int tap = 0; tap < 9; ++tap) {
    int kh = tap / 3, kw = tap % 3;
    int gy = refl(y + kh - 1), gx = refl(xq + kw - 1);
    v[tap] = xb[(gy * 64 + gx) * 64 + lane];
    s += (double)v[tap] * (double)v[tap];
  }
#pragma unroll
  for (int off = 32; off; off >>= 1) s += __shfl_xor(s, off, 64);
  double n = sqrt(s);
  if (n < 1e-12) n = 1e-12;
  if (lane == 0) dinv[b * 4096 + l] = 1.0 / n;
  float inv = (float)(1.0 / n);
#pragma unroll
  for (int tap = 0; tap < 9; ++tap) {
    __hip_fp8_e4m3 h(v[tap] * inv);
    U[tap * 512 + (lane >> 4) * 128 + p * 16 + (lane & 15)] = h.__x;
  }
  __syncthreads();
  uint8_t* g = Xq + (size_t)rbg * 4608;
  if (t < 288) *(uint4*)&g[t * 16] = *(const uint4*)&U[t * 16];
}

// ---- 3x3 conv as implicit-im2col bf16 MFMA GEMM (R15-proven)
__global__ __launch_bounds__(256) void k_cgemm(const float* __restrict__ in_t,
                                               const ushort_t* __restrict__ Wt,
                                               const float* __restrict__ bias,
                                               float* __restrict__ out_t,
                                               int do_relu) {
  __shared__ __align__(16) ushort_t Ab[2][2048];
  __shared__ __align__(16) ushort_t Bb[2][2048];
  int t = threadIdx.x;
  int w = t >> 6, lane = t & 63, rr = lane & 31, half = lane >> 5;
  int mi = w >> 1, ni = w & 1;
  int bid = blockIdx.x;
  int b = bid >> 6, y = bid & 63;
  const float* xrow = in_t + ((size_t)b * 4096) * 64;
  int sr = t >> 2, sq = t & 3;

  float bz = bias[ni * 32 + rr];
  f32x16 acc;
#pragma unroll
  for (int q = 0; q < 16; ++q) acc[q] = bz;

#define STAGE_CONV(kc_, buf_)                                                   \
  {                                                                             \
    int tap = (kc_) >> 1, ch = ((kc_) & 1) * 32 + sq * 8;                       \
    int kh = tap / 3, kw = tap % 3;                                             \
    int gy = y + kh - 1, gx = sr + kw - 1;                                      \
    ushort_t tmp[8];                                                            \
    if (gy >= 0 && gy < 64 && gx >= 0 && gx < 64) {                             \
      const float* src = xrow + ((size_t)(gy * 64 + gx)) * 64 + ch;             \
      float4 v0 = *(const float4*)src;                                          \
      float4 v1 = *(const float4*)(src + 4);                                    \
      float vv[8] = {v0.x, v0.y, v0.z, v0.w, v1.x, v1.y, v1.z, v1.w};           \
      _Pragma("unroll") for (int j = 0; j < 8; ++j) {                           \
        __hip_bfloat16 h = __float2bfloat16(vv[j]);                             \
        tmp[j] = *(ushort_t*)&h;                                                \
      }                                                                         \
    } else {                                                                    \
      _Pragma("unroll") for (int j = 0; j < 8; ++j) tmp[j] = 0;                 \
    }                                                                           \
    *(uint4*)&Ab[buf_][(sr >> 3) * 256 + sq * 64 + (sr & 7) * 8] = *(uint4*)tmp;\
    gload_lds16(Wt + (size_t)(t >> 5) * 4608 + (kc_) * 256 + (t & 31) * 8,      \
                &Bb[buf_][t * 8]);                                              \
  }

  STAGE_CONV(0, 0)
#pragma unroll 2
  for (int kc = 0; kc < 18; ++kc) {
    __syncthreads();
    if (kc < 17) STAGE_CONV(kc + 1, (kc + 1) & 1)
    const ushort_t* tA = Ab[kc & 1];
    const ushort_t* tB = Bb[kc & 1];
#pragma unroll
    for (int ks = 0; ks < 2; ++ks) {
      int seg8 = (ks * 2 + half) * 8 + (rr & 7);
      short8 af = *(const short8*)&tA[(mi * 4 + (rr >> 3)) * 256 + seg8 * 8];
      short8 bf = *(const short8*)&tB[(ni * 4 + (rr >> 3)) * 256 + seg8 * 8];
      acc = __builtin_amdgcn_mfma_f32_32x32x16_bf16(af, bf, acc, 0, 0, 0);
    }
  }
#undef STAGE_CONV
  float* orow = out_t + ((size_t)b * 4096 + y * 64) * 64;
  int n = ni * 32 + rr;
#pragma unroll
  for (int reg = 0; reg < 16; ++reg) {
    int m = mi * 32 + (reg & 3) + 8 * (reg >> 2) + 4 * half;
    float vv = acc[reg];
    if (do_relu) vv = fmaxf(vv, 0.f);
    orow[m * 64 + n] = vv;
  }
}

// -------- fp8 Gram via MX-scaled MFMA 32x32x64 (unit scales) — R16-proven
__global__ __launch_bounds__(256, 4) void k_gram(const uint8_t* __restrict__ Xq,
                                                 int* __restrict__ pidx) {
  __shared__ __align__(16) char lds[40960];
  uint8_t* sAb = (uint8_t*)lds;             // 2 bufs x 16KB
  uint8_t* sBb = (uint8_t*)(lds + 32768);   // 2 bufs x 4KB

  int wg = blockIdx.x;
  int u = wg & 7, v = wg >> 3;
  int bs = u + 8 * (v & 1);        // (b,sp) group: 2 per XCD
  int b = bs >> 2, sp = bs & 3;
  int cb = v >> 1;                 // 0..63
  int colbase = cb * 64;
  int t = threadIdx.x;
  int w = t >> 6, lane = t & 63;
  int rr = lane & 31, half = lane >> 5;
  int rb8 = rr >> 3, r8 = rr & 7;
  int so0 = (2 * half) * 8 + r8;
  int so1 = so0 + 8;

  const uint8_t* Xb = Xq + (size_t)b * 512 * 4608;
  const uint8_t* XB = Xb + (size_t)(cb * 8) * 4608;

  unsigned list[8];
#pragma unroll
  for (int j = 0; j < 8; ++j) list[j] = 0u;

#pragma unroll 1
  for (int mt = 0; mt < 4; ++mt) {
    int rowbase = sp * 1024 + mt * 256;
    __syncthreads();
    const uint8_t* XA = Xb + (size_t)(sp * 128 + mt * 32) * 4608;
    f32x16 acc[2][2];
#pragma unroll
    for (int im = 0; im < 2; ++im)
#pragma unroll
      for (int il = 0; il < 2; ++il)
#pragma unroll
        for (int q = 0; q < 16; ++q) acc[im][il][q] = 0.f;
    {
#pragma unroll
      for (int j = 0; j < 4; ++j) {
        int s = j * 256 + t;
        gload_lds16(XA + (size_t)(s >> 5) * 4608 + (s & 31) * 16, sAb + s * 16);
      }
      gload_lds16(XB + (size_t)(t >> 5) * 4608 + (t & 31) * 16, sBb + t * 16);
    }
#pragma unroll 1
    for (int kc = 0; kc < 9; ++kc) {
      __syncthreads();
      if (kc < 8) {
        int buf = (kc + 1) & 1;
        int ko = (kc + 1) * 512;
#pragma unroll
        for (int j = 0; j < 4; ++j) {
          int s = j * 256 + t;
          gload_lds16(XA + (size_t)(s >> 5) * 4608 + ko + (s & 31) * 16,
                      sAb + buf * 16384 + s * 16);
        }
        gload_lds16(XB + (size_t)(t >> 5) * 4608 + ko + (t & 31) * 16,
                    sBb + buf * 4096 + t * 16);
      }
      const uint8_t* tA = sAb + (kc & 1) * 16384;
      const uint8_t* tB = sBb + (kc & 1) * 4096;
      i32x8 af[2], bf[2];
#pragma unroll
      for (int im = 0; im < 2; ++im) {
        int rbA = w * 8 + im * 4 + rb8;
        af[im] = ldfrag(&tA[(rbA * 32 + so0) * 16], &tA[(rbA * 32 + so1) * 16]);
      }
#pragma unroll
      for (int il = 0; il < 2; ++il) {
        int rbB = il * 4 + rb8;
        bf[il] = ldfrag(&tB[(rbB * 32 + so0) * 16], &tB[(rbB * 32 + so1) * 16]);
      }
      acc[0][0] = __builtin_amdgcn_mfma_scale_f32_32x32x64_f8f6f4(
          af[0], bf[0], acc[0][0], 0, 0, 0, 0x7F7F7F7F, 0, 0x7F7F7F7F);
      acc[0][1] = __builtin_amdgcn_mfma_scale_f32_32x32x64_f8f6f4(
          af[0], bf[1], acc[0][1], 0, 0, 0, 0x7F7F7F7F, 0, 0x7F7F7F7F);
      acc[1][0] = __builtin_amdgcn_mfma_scale_f32_32x32x64_f8f6f4(
          af[1], bf[0], acc[1][0], 0, 0, 0, 0x7F7F7F7F, 0, 0x7F7F7F7F);
      acc[1][1] = __builtin_amdgcn_mfma_scale_f32_32x32x64_f8f6f4(
          af[1], bf[1], acc[1][1], 0, 0, 0, 0x7F7F7F7F, 0, 0x7F7F7F7F);
    }
    int rowb = rowbase + w * 64;
#pragma unroll
    for (int im = 0; im < 2; ++im) {
#pragma unroll
      for (int reg = 0; reg < 16; ++reg) {
        float a0 = acc[im][0][reg], a1 = acc[im][1][reg];
        float vo = half ? a1 : a0;
        float vs = half ? a0 : a1;
        float vr = __shfl_xor(vs, 32, 64);
        int rbase = rowb + im * 32 + (reg & 3) + 8 * (reg >> 2);
        ins8(list, packval(vo, rbase + 4 * half));
        ins8(list, packval(vr, rbase + 4 * (1 - half)));
      }
    }
  }
  __syncthreads();
  unsigned* M = (unsigned*)lds;
#pragma unroll
  for (int j = 0; j < 8; ++j) M[lane * 33 + w * 8 + j] = list[j];
  __syncthreads();
  if (t < 64) {
    unsigned bl[8];
#pragma unroll
    for (int j = 0; j < 8; ++j) bl[j] = 0u;
#pragma unroll 1
    for (int i = 0; i < 32; ++i) ins8(bl, M[t * 33 + i]);
    size_t base = (((size_t)b * 4 + sp) * 4096 + colbase + t) * 8;
#pragma unroll
    for (int j = 0; j < 8; ++j) pidx[base + j] = (int)bl[j];
  }
}

// ---- fp8-top-8 tournament, then exact f64 refine (R13-proven)
__global__ __launch_bounds__(256) void k_refine(const float* __restrict__ xt,
                                                const double* __restrict__ dinv,
                                                const int* __restrict__ pidx,
                                                float* __restrict__ Sval,
                                                int* __restrict__ Sidx) {
  int w = threadIdx.x >> 6, lane = threadIdx.x & 63;
  int gl = blockIdx.x * 4 + w;
  int b = gl >> 12, l = gl & 4095;
  int y = l >> 6, xq = l & 63;
  const float* xb = xt + ((size_t)b * 4096) * 64;
  unsigned cp = 0u;
  if (lane < 32) {
    int sp = lane >> 3, j = lane & 7;
    cp = (unsigned)pidx[(((size_t)b * 4 + sp) * 4096 + l) * 8 + j];
  }
  int wm[8];
#pragma unroll
  for (int r = 0; r < 8; ++r) {
    unsigned v = cp;
#pragma unroll
    for (int off = 32; off; off >>= 1) {
      unsigned ov = __shfl_xor(v, off, 64);
      v = ov > v ? ov : v;
    }
    wm[r] = (int)(v & 4095u);
    if (cp == v) cp = 0u;
  }
  int ch4 = (lane & 15) * 4;
  float4 xl4[9];
#pragma unroll
  for (int tap = 0; tap < 9; ++tap) {
    int kh = tap / 3, kw = tap % 3;
    xl4[tap] = *(const float4*)&xb[(refl(y + kh - 1) * 64 + refl(xq + kw - 1)) * 64 + ch4];
  }
  double il = dinv[b * 4096 + l];
  double rv = -1e30;
  int ridx = 0x7fffffff;
#pragma unroll
  for (int it = 0; it < 2; ++it) {
    int m = wm[it * 4 + (lane >> 4)];
    int my = m >> 6, mx = m & 63;
    double d = 0.0;
#pragma unroll
    for (int tap = 0; tap < 9; ++tap) {
      int kh = tap / 3, kw = tap % 3;
      float4 gv = *(const float4*)&xb[(refl(my + kh - 1) * 64 + refl(mx + kw - 1)) * 64 + ch4];
      d += (double)xl4[tap].x * (double)gv.x + (double)xl4[tap].y * (double)gv.y +
           (double)xl4[tap].z * (double)gv.z + (double)xl4[tap].w * (double)gv.w;
    }
#pragma unroll
    for (int off = 1; off < 16; off <<= 1) d += __shfl_xor(d, off, 64);
    double R = d * il * dinv[b * 4096 + m];
    double Rsrc = __shfl(R, (lane & 3) * 16, 64);
    int msrc = __shfl(m, (lane & 3) * 16, 64);
    if ((lane >> 2) == it && lane < 8) { rv = Rsrc; ridx = msrc; }
  }
#pragma unroll
  for (int r = 0; r < 5; ++r) {
    double v = rv;
    int i = ridx;
#pragma unroll
    for (int off = 32; off; off >>= 1) {
      double ov = __shfl_xor(v, off, 64);
      int oi = __shfl_xor(i, off, 64);
      if (ov > v || (ov == v && oi < i)) { v = ov; i = oi; }
    }
    if (r >= 1 && lane == 0) {
      Sval[((size_t)b * 5 + r) * 4096 + l] = (float)v;
      Sidx[((size_t)b * 5 + r) * 4096 + l] = i;
    }
    if (rv == v && ridx == i) rv = -1e30;
  }
}

// ---- texture gather -> full 384-deep bf16 tiled input (feat|x|texture)
// 16 px/block, grid 1024. Xb16[rb(2048/batch... global rb = px/8)][kc12][seg][r8][e]
__global__ __launch_bounds__(256, 4) void k_tex(const float* __restrict__ xt,
                                                const float* __restrict__ feat,
                                                const float* __restrict__ Sval,
                                                const int* __restrict__ Sidx,
                                                ushort_t* __restrict__ Xb16) {
  __shared__ ushort_t U[6144];    // 2 rbs x 3072
  __shared__ int SI[3 * 18 * 4];
  __shared__ float SV[16 * 4];
  int t = threadIdx.x;
  int w = t >> 6, lane = t & 63;
  int p0 = blockIdx.x * 16;
  int b = p0 >> 12, pl = p0 & 4095;
  int y0 = pl >> 6, x0 = pl & 63;
  if (t < 216) {
    int r = t / 72, rem = t % 72;
    int c = rem >> 2, i = (rem & 3) + 1;
    int qy = y0 - 1 + r, qx = x0 - 1 + c;
    int m = 0x7fffffff;
    if (qy >= 0 && qy < 64 && qx >= 0 && qx < 64)
      m = Sidx[((size_t)b * 5 + i) * 4096 + qy * 64 + qx] & 4095;
    SI[(r * 18 + c) * 4 + (i - 1)] = m;
  }
  if (t < 64) {
    int px = t >> 2, i = (t & 3) + 1;
    SV[px * 4 + (i - 1)] = Sval[((size_t)b * 5 + i) * 4096 + pl + px];
  }
#pragma unroll
  for (int jj = 0; jj < 4; ++jj) {
    int px = w * 4 + jj;
    float fv = feat[((size_t)b * 4096 + pl + px) * 64 + lane];
    float xv = xt[((size_t)b * 4096 + pl + px) * 64 + lane];
    __hip_bfloat16 hf = __float2bfloat16(fv);
    __hip_bfloat16 hx = __float2bfloat16(xv);
    U[toff(px, lane, 3072)] = *(ushort_t*)&hf;
    U[toff(px, 64 + lane, 3072)] = *(ushort_t*)&hx;
  }
  __syncthreads();
  const float* xb = xt + ((size_t)b * 4096) * 64;
#pragma unroll 4
  for (int k = 0; k < 16; ++k) {
    int pr = w * 16 + k;
    int px = pr >> 2, i = pr & 3;
    float a = 0.f;
#pragma unroll
    for (int tap = 0; tap < 9; ++tap) {
      int kh = tap / 3, kw = tap % 3;
      int m = SI[((2 - kh) * 18 + px + 2 - kw) * 4 + i];
      if (m != 0x7fffffff) {
        int gy = refl((m >> 6) + kh - 1), gx = refl((m & 63) + kw - 1);
        a += xb[(gy * 64 + gx) * 64 + lane];
      }
    }
    __hip_bfloat16 h = __float2bfloat16(a * SV[px * 4 + i] * (1.f / 9.f));
    U[toff(px, 128 + i * 64 + lane, 3072)] = *(ushort_t*)&h;
  }
  __syncthreads();
  ushort_t* g = Xb16 + (size_t)blockIdx.x * 6144;
#pragma unroll
  for (int i = 0; i < 3; ++i) {
    int s = i * 256 + t;
    *(uint4*)&g[s * 8] = *(const uint4*)&U[s * 8];
  }
}

// ---- final 1x1: bf16 MFMA GEMM K=384 (A,B pre-tiled), NCHW via LDS transpose
__global__ __launch_bounds__(256) void k_outg(const ushort_t* __restrict__ Xb16,
                                              const ushort_t* __restrict__ Wcatb,
                                              const float* __restrict__ beff,
                                              float* __restrict__ out) {
  __shared__ __align__(16) ushort_t Ab[2][2048];
  __shared__ __align__(16) ushort_t Bb[2][2048];
  __shared__ float T[64 * 65];
  int t = threadIdx.x;
  int w = t >> 6, lane = t & 63, rr = lane & 31, half = lane >> 5;
  int mi = w >> 1, ni = w & 1;
  int bid = blockIdx.x;
  int b = bid >> 6, y = bid & 63;
  const ushort_t* XA = Xb16 + (size_t)bid * 24576;  // 8 rbs x 3072

  float bz = beff[ni * 32 + rr];
  f32x16 acc;
#pragma unroll
  for (int q = 0; q < 16; ++q) acc[q] = bz;

#define STAGE_OUT(kc_, buf_)                                                    \
  {                                                                             \
    gload_lds16(XA + (size_t)(t >> 5) * 3072 + (kc_) * 256 + (t & 31) * 8,      \
                &Ab[buf_][t * 8]);                                              \
    gload_lds16(Wcatb + (size_t)(t >> 5) * 3072 + (kc_) * 256 + (t & 31) * 8,   \
                &Bb[buf_][t * 8]);                                              \
  }

  STAGE_OUT(0, 0)
#pragma unroll 2
  for (int kc = 0; kc < 12; ++kc) {
    __syncthreads();
    if (kc < 11) STAGE_OUT(kc + 1, (kc + 1) & 1)
    const ushort_t* tA = Ab[kc & 1];
    const ushort_t* tB = Bb[kc & 1];
#pragma unroll
    for (int ks = 0; ks < 2; ++ks) {
      int seg8 = (ks * 2 + half) * 8 + (rr & 7);
      short8 af = *(const short8*)&tA[(mi * 4 + (rr >> 3)) * 256 + seg8 * 8];
      short8 bf = *(const short8*)&tB[(ni * 4 + (rr >> 3)) * 256 + seg8 * 8];
      acc = __builtin_amdgcn_mfma_f32_32x32x16_bf16(af, bf, acc, 0, 0, 0);
    }
  }
#undef STAGE_OUT
  __syncthreads();
  int n = ni * 32 + rr;
#pragma unroll
  for (int reg = 0; reg < 16; ++reg) {
    int m = mi * 32 + (reg & 3) + 8 * (reg >> 2) + 4 * half;
    T[m * 65 + n] = acc[reg];
  }
  __syncthreads();
  int n2 = t >> 2, grp = t & 3;
  float o[16];
#pragma unroll
  for (int j = 0; j < 16; ++j) o[j] = T[(grp * 16 + j) * 65 + n2];
  float* od = out + ((size_t)b * 64 + n2) * 4096 + y * 64 + grp * 16;
#pragma unroll
  for (int j = 0; j < 4; ++j) *(float4*)(od + j * 4) = *(float4*)&o[j * 4];
}

// ---------------------------------------------------------------------- launch
extern "C" void kernel_launch(void* const* d_in, const int* in_sizes, int n_in,
                              void* d_out, int out_size, void* d_ws, size_t ws_size,
                              hipStream_t stream) {
  const float* x = (const float*)d_in[0];
  const float* w1 = (const float*)d_in[1];
  const float* b1 = (const float*)d_in[2];
  const float* w2 = (const float*)d_in[3];
  const float* b2 = (const float*)d_in[4];
  const float* wt1 = (const float*)d_in[5];
  const float* bt1 = (const float*)d_in[6];
  const float* wt2 = (const float*)d_in[7];
  const float* bt2 = (const float*)d_in[8];

  char* ws = (char*)d_ws;
  float* x_t = (float*)(ws + 0);                       //  4 MB NHWC x
  float* y1 = (float*)(ws + 4194304);                  //  4 MB relu(conv1)
  float* feat = (float*)(ws + 8388608);                //  4 MB conv2
  uint8_t* Xq = (uint8_t*)(ws + 12582912);             //  9.4 MB fp8 qn unfold
  ushort_t* Xb16 = (ushort_t*)(ws + 12582912);         // 12.6 MB (aliases Xq —
                                                       //  written after gram)
  double* dinv = (double*)(ws + 31457280);             // 128 KB f64 1/norm
  int* pidx = (int*)(ws + 31653888);                   //  2 MB
  float* Sval = (float*)(ws + 33751040);               // 320 KB
  int* Sidx = (int*)(ws + 34078720);                   // 320 KB
  ushort_t* Wb1t = (ushort_t*)(ws + 34406400);         // 72 KB bf16 tiled W1
  ushort_t* Wb2t = (ushort_t*)(ws + 34553856);         // 72 KB bf16 tiled W2
  ushort_t* Wcatb = (ushort_t*)(ws + 34701312);        // 48 KB bf16 tiled Wcat
  float* beff = (float*)(ws + 34799616);               // 256 B
  float* out = (float*)d_out;

  k_prep<<<dim3(641), dim3(256), 0, stream>>>(x, x_t, w1, w2, wt1, bt1, wt2, bt2,
                                              Wb1t, Wb2t, Wcatb, beff);
  k_unfold<<<dim3(2048), dim3(512), 0, stream>>>(x_t, Xq, dinv);
  k_cgemm<<<dim3(256), dim3(256), 0, stream>>>(x_t, Wb1t, b1, y1, 1);
  k_cgemm<<<dim3(256), dim3(256), 0, stream>>>(y1, Wb2t, b2, feat, 0);
  k_gram<<<dim3(1024), dim3(256), 0, stream>>>(Xq, pidx);
  k_refine<<<dim3(4096), dim3(256), 0, stream>>>(x_t, dinv, pidx, Sval, Sidx);
  k_tex<<<dim3(1024), dim3(256), 0, stream>>>(x_t, feat, Sval, Sidx, Xb16);
  k_outg<<<dim3(256), dim3(256), 0, stream>>>(Xb16, Wcatb, beff, out);
}

// Round 18
// 255.230 us; speedup vs baseline: 1.5552x; 1.0914x over previous
//
#include <hip/hip_runtime.h>
#include <hip/hip_bf16.h>
#include <hip/hip_fp8.h>
#include <stdint.h>

typedef unsigned short ushort_t;
typedef __attribute__((ext_vector_type(8))) short short8;
typedef __attribute__((ext_vector_type(16))) float f32x16;
typedef __attribute__((ext_vector_type(8))) int i32x8;
typedef __attribute__((ext_vector_type(4))) int i32x4;

#define DEV __device__ __forceinline__

DEV int refl(int j) { return j < 0 ? -j : (j > 63 ? 126 - j : j); }

DEV void gload_lds16(const void* g, void* l) {
  __builtin_amdgcn_global_load_lds(
      (const __attribute__((address_space(1))) unsigned int*)g,
      (__attribute__((address_space(3))) unsigned int*)l, 16, 0, 0);
}

// packed candidate: values are R in [-1.03,1.03]; v+2.0f > 0 so its uint is
// monotone. top-20 bits | 12-bit row index. (3 VALU: add, and, or)
DEV unsigned packval(float v, int idx) {
  return (__float_as_uint(v + 2.0f) & 0xFFFFF000u) | (unsigned)idx;
}

// sorted-desc 8-slot insert via max/min bubble-through (16 VALU, no branches)
DEV void ins8(unsigned (&s)[8], unsigned p) {
#pragma unroll
  for (int j = 0; j < 8; ++j) {
    unsigned mx = s[j] > p ? s[j] : p;
    unsigned mn = s[j] > p ? p : s[j];
    s[j] = mx;
    p = mn;
  }
}

// two 16B LDS granules -> v8i32 MFMA fragment (K=64 fp8 bytes per lane-row)
DEV i32x8 ldfrag(const uint8_t* p0, const uint8_t* p1) {
  i32x4 lo = *(const i32x4*)p0;
  i32x4 hi = *(const i32x4*)p1;
  i32x8 r;
  r[0] = lo[0]; r[1] = lo[1]; r[2] = lo[2]; r[3] = lo[3];
  r[4] = hi[0]; r[5] = hi[1]; r[6] = hi[2]; r[7] = hi[3];
  return r;
}

// tiled bf16 offset (rb stride given): row r, depth d
DEV int toff(int r, int d, int rbstride) {
  return (r >> 3) * rbstride + (d >> 5) * 256 + ((d >> 3) & 3) * 64 + (r & 7) * 8 + (d & 7);
}

// ---- fused NCHW->NHWC transpose + weights prep
__global__ __launch_bounds__(256) void k_prep(
    const float* __restrict__ x, float* __restrict__ xt,
    const float* __restrict__ w1, const float* __restrict__ w2,
    const float* __restrict__ wt1, const float* __restrict__ bt1,
    const float* __restrict__ wt2, const float* __restrict__ bt2,
    ushort_t* __restrict__ Wb1t, ushort_t* __restrict__ Wb2t,
    ushort_t* __restrict__ Wcatb, float* __restrict__ beff) {
  int t = threadIdx.x;
  if (blockIdx.x < 256) {
    __shared__ float tile[64][65];
    int wg = blockIdx.x;
    int b = wg >> 6, pt = wg & 63;
    int lane = t & 63, grp = t >> 6;
    const float* xb = x + ((size_t)b * 64) * 4096 + pt * 64;
#pragma unroll
    for (int j = 0; j < 16; ++j) {
      int c = j * 4 + grp;
      tile[c][lane] = xb[(size_t)c * 4096 + lane];
    }
    __syncthreads();
    float* xtb = xt + ((size_t)b * 4096 + (size_t)pt * 64) * 64;
#pragma unroll
    for (int j = 0; j < 16; ++j) {
      int p = j * 4 + grp;
      xtb[p * 64 + lane] = tile[lane][p];
    }
    return;
  }
  int id = (blockIdx.x - 256) * 256 + t;
  if (id < 36864) {
    int n = id & 63, d = id >> 6;
    __hip_bfloat16 h = __float2bfloat16(w1[(n * 64 + (d & 63)) * 9 + (d >> 6)]);
    Wb1t[toff(n, d, 4608)] = *(ushort_t*)&h;
  } else if (id < 73728) {
    int rel = id - 36864;
    int n = rel & 63, d = rel >> 6;
    __hip_bfloat16 h = __float2bfloat16(w2[(n * 64 + (d & 63)) * 9 + (d >> 6)]);
    Wb2t[toff(n, d, 4608)] = *(ushort_t*)&h;
  } else if (id < 98304) {
    int rel = id - 73728;
    int n = rel & 63, d = rel >> 6;  // d in [0,384)
    float s;
    if (d < 128) {
      s = wt2[n * 192 + d];
    } else {
      int j = d - 128;
      s = 0.f;
      for (int ct = 0; ct < 64; ++ct) s += wt2[n * 192 + 128 + ct] * wt1[ct * 256 + j];
    }
    __hip_bfloat16 h = __float2bfloat16(s);
    Wcatb[toff(n, d, 3072)] = *(ushort_t*)&h;
  } else if (id < 98368) {
    int co = id - 98304;
    float s = bt2[co];
    for (int ct = 0; ct < 64; ++ct) s += wt2[co * 192 + 128 + ct] * bt1[ct];
    beff[co] = s;
  }
}

// ---- conv body: implicit-im2col bf16 MFMA GEMM (R15-proven), smem = 16KB
DEV void conv_body(char* smem, int bid, const float* __restrict__ in_t,
                   const ushort_t* __restrict__ Wt, const float* __restrict__ bias,
                   float* __restrict__ out_t, int do_relu, int t) {
  ushort_t* Ab = (ushort_t*)smem;            // 2 x 2048
  ushort_t* Bb = (ushort_t*)(smem + 8192);   // 2 x 2048
  int w = t >> 6, lane = t & 63, rr = lane & 31, half = lane >> 5;
  int mi = w >> 1, ni = w & 1;
  int b = bid >> 6, y = bid & 63;
  const float* xrow = in_t + ((size_t)b * 4096) * 64;
  int sr = t >> 2, sq = t & 3;

  float bz = bias[ni * 32 + rr];
  f32x16 acc;
#pragma unroll
  for (int q = 0; q < 16; ++q) acc[q] = bz;

#define STAGE_CONV(kc_, buf_)                                                   \
  {                                                                             \
    int tap = (kc_) >> 1, ch = ((kc_) & 1) * 32 + sq * 8;                       \
    int kh = tap / 3, kw = tap % 3;                                             \
    int gy = y + kh - 1, gx = sr + kw - 1;                                      \
    ushort_t tmp[8];                                                            \
    if (gy >= 0 && gy < 64 && gx >= 0 && gx < 64) {                             \
      const float* src = xrow + ((size_t)(gy * 64 + gx)) * 64 + ch;             \
      float4 v0 = *(const float4*)src;                                          \
      float4 v1 = *(const float4*)(src + 4);                                    \
      float vv[8] = {v0.x, v0.y, v0.z, v0.w, v1.x, v1.y, v1.z, v1.w};           \
      _Pragma("unroll") for (int j = 0; j < 8; ++j) {                           \
        __hip_bfloat16 h = __float2bfloat16(vv[j]);                             \
        tmp[j] = *(ushort_t*)&h;                                                \
      }                                                                         \
    } else {                                                                    \
      _Pragma("unroll") for (int j = 0; j < 8; ++j) tmp[j] = 0;                 \
    }                                                                           \
    *(uint4*)&Ab[(buf_)*2048 + (sr >> 3) * 256 + sq * 64 + (sr & 7) * 8] =      \
        *(uint4*)tmp;                                                           \
    gload_lds16(Wt + (size_t)(t >> 5) * 4608 + (kc_) * 256 + (t & 31) * 8,      \
                &Bb[(buf_)*2048 + t * 8]);                                      \
  }

  STAGE_CONV(0, 0)
#pragma unroll 2
  for (int kc = 0; kc < 18; ++kc) {
    __syncthreads();
    if (kc < 17) STAGE_CONV(kc + 1, (kc + 1) & 1)
    const ushort_t* tA = Ab + (kc & 1) * 2048;
    const ushort_t* tB = Bb + (kc & 1) * 2048;
#pragma unroll
    for (int ks = 0; ks < 2; ++ks) {
      int seg8 = (ks * 2 + half) * 8 + (rr & 7);
      short8 af = *(const short8*)&tA[(mi * 4 + (rr >> 3)) * 256 + seg8 * 8];
      short8 bf = *(const short8*)&tB[(ni * 4 + (rr >> 3)) * 256 + seg8 * 8];
      acc = __builtin_amdgcn_mfma_f32_32x32x16_bf16(af, bf, acc, 0, 0, 0);
    }
  }
#undef STAGE_CONV
  float* orow = out_t + ((size_t)b * 4096 + y * 64) * 64;
  int n = ni * 32 + rr;
#pragma unroll
  for (int reg = 0; reg < 16; ++reg) {
    int m = mi * 32 + (reg & 3) + 8 * (reg >> 2) + 4 * half;
    float vv = acc[reg];
    if (do_relu) vv = fmaxf(vv, 0.f);
    orow[m * 64 + n] = vv;
  }
}

// ---- fuseA: unfold->fp8 qn tiled (blocks 0..2047) || conv1 (2048..2303)
__global__ __launch_bounds__(256) void k_fuseA(
    const float* __restrict__ xt, uint8_t* __restrict__ Xq,
    double* __restrict__ dinv, const ushort_t* __restrict__ Wb1t,
    const float* __restrict__ b1, float* __restrict__ y1) {
  __shared__ __align__(16) char smem[16384];
  int t = threadIdx.x;
  if (blockIdx.x >= 2048) {
    conv_body(smem, blockIdx.x - 2048, xt, Wb1t, b1, y1, 1, t);
    return;
  }
  uint8_t* U = (uint8_t*)smem;
  int rbg = blockIdx.x;
  int b = rbg >> 9, rb = rbg & 511;
  int wv = t >> 6, lane = t & 63;
  const float* xb = xt + ((size_t)b * 4096) * 64;
#pragma unroll
  for (int pp = 0; pp < 2; ++pp) {
    int p = wv * 2 + pp;
    int l = rb * 8 + p;
    int y = l >> 6, xq = l & 63;
    float v[9];
    double s = 0.0;
#pragma unroll
    for (int tap = 0; tap < 9; ++tap) {
      int kh = tap / 3, kw = tap % 3;
      int gy = refl(y + kh - 1), gx = refl(xq + kw - 1);
      v[tap] = xb[(gy * 64 + gx) * 64 + lane];
      s += (double)v[tap] * (double)v[tap];
    }
#pragma unroll
    for (int off = 32; off; off >>= 1) s += __shfl_xor(s, off, 64);
    double n = sqrt(s);
    if (n < 1e-12) n = 1e-12;
    if (lane == 0) dinv[b * 4096 + l] = 1.0 / n;
    float inv = (float)(1.0 / n);
#pragma unroll
    for (int tap = 0; tap < 9; ++tap) {
      __hip_fp8_e4m3 h(v[tap] * inv);
      U[tap * 512 + (lane >> 4) * 128 + p * 16 + (lane & 15)] = h.__x;
    }
  }
  __syncthreads();
  uint8_t* g = Xq + (size_t)rbg * 4608;
  {
    *(uint4*)&g[t * 16] = *(const uint4*)&U[t * 16];
    if (t < 32) *(uint4*)&g[(256 + t) * 16] = *(const uint4*)&U[(256 + t) * 16];
  }
}

// ---- conv2 standalone
__global__ __launch_bounds__(256) void k_cgemm(const float* __restrict__ in_t,
                                               const ushort_t* __restrict__ Wt,
                                               const float* __restrict__ bias,
                                               float* __restrict__ out_t,
                                               int do_relu) {
  __shared__ __align__(16) char smem[16384];
  conv_body(smem, blockIdx.x, in_t, Wt, bias, out_t, do_relu, threadIdx.x);
}

// -------- fp8 Gram via MX-scaled MFMA 32x32x64 (unit scales) — R16-proven
__global__ __launch_bounds__(256, 4) void k_gram(const uint8_t* __restrict__ Xq,
                                                 int* __restrict__ pidx) {
  __shared__ __align__(16) char lds[40960];
  uint8_t* sAb = (uint8_t*)lds;             // 2 bufs x 16KB
  uint8_t* sBb = (uint8_t*)(lds + 32768);   // 2 bufs x 4KB

  int wg = blockIdx.x;
  int u = wg & 7, v = wg >> 3;
  int bs = u + 8 * (v & 1);        // (b,sp) group: 2 per XCD
  int b = bs >> 2, sp = bs & 3;
  int cb = v >> 1;                 // 0..63
  int colbase = cb * 64;
  int t = threadIdx.x;
  int w = t >> 6, lane = t & 63;
  int rr = lane & 31, half = lane >> 5;
  int rb8 = rr >> 3, r8 = rr & 7;
  int so0 = (2 * half) * 8 + r8;
  int so1 = so0 + 8;

  const uint8_t* Xb = Xq + (size_t)b * 512 * 4608;
  const uint8_t* XB = Xb + (size_t)(cb * 8) * 4608;

  unsigned list[8];
#pragma unroll
  for (int j = 0; j < 8; ++j) list[j] = 0u;

#pragma unroll 1
  for (int mt = 0; mt < 4; ++mt) {
    int rowbase = sp * 1024 + mt * 256;
    __syncthreads();
    const uint8_t* XA = Xb + (size_t)(sp * 128 + mt * 32) * 4608;
    f32x16 acc[2][2];
#pragma unroll
    for (int im = 0; im < 2; ++im)
#pragma unroll
      for (int il = 0; il < 2; ++il)
#pragma unroll
        for (int q = 0; q < 16; ++q) acc[im][il][q] = 0.f;
    {
#pragma unroll
      for (int j = 0; j < 4; ++j) {
        int s = j * 256 + t;
        gload_lds16(XA + (size_t)(s >> 5) * 4608 + (s & 31) * 16, sAb + s * 16);
      }
      gload_lds16(XB + (size_t)(t >> 5) * 4608 + (t & 31) * 16, sBb + t * 16);
    }
#pragma unroll 1
    for (int kc = 0; kc < 9; ++kc) {
      __syncthreads();
      if (kc < 8) {
        int buf = (kc + 1) & 1;
        int ko = (kc + 1) * 512;
#pragma unroll
        for (int j = 0; j < 4; ++j) {
          int s = j * 256 + t;
          gload_lds16(XA + (size_t)(s >> 5) * 4608 + ko + (s & 31) * 16,
                      sAb + buf * 16384 + s * 16);
        }
        gload_lds16(XB + (size_t)(t >> 5) * 4608 + ko + (t & 31) * 16,
                    sBb + buf * 4096 + t * 16);
      }
      const uint8_t* tA = sAb + (kc & 1) * 16384;
      const uint8_t* tB = sBb + (kc & 1) * 4096;
      i32x8 af[2], bf[2];
#pragma unroll
      for (int im = 0; im < 2; ++im) {
        int rbA = w * 8 + im * 4 + rb8;
        af[im] = ldfrag(&tA[(rbA * 32 + so0) * 16], &tA[(rbA * 32 + so1) * 16]);
      }
#pragma unroll
      for (int il = 0; il < 2; ++il) {
        int rbB = il * 4 + rb8;
        bf[il] = ldfrag(&tB[(rbB * 32 + so0) * 16], &tB[(rbB * 32 + so1) * 16]);
      }
      acc[0][0] = __builtin_amdgcn_mfma_scale_f32_32x32x64_f8f6f4(
          af[0], bf[0], acc[0][0], 0, 0, 0, 0x7F7F7F7F, 0, 0x7F7F7F7F);
      acc[0][1] = __builtin_amdgcn_mfma_scale_f32_32x32x64_f8f6f4(
          af[0], bf[1], acc[0][1], 0, 0, 0, 0x7F7F7F7F, 0, 0x7F7F7F7F);
      acc[1][0] = __builtin_amdgcn_mfma_scale_f32_32x32x64_f8f6f4(
          af[1], bf[0], acc[1][0], 0, 0, 0, 0x7F7F7F7F, 0, 0x7F7F7F7F);
      acc[1][1] = __builtin_amdgcn_mfma_scale_f32_32x32x64_f8f6f4(
          af[1], bf[1], acc[1][1], 0, 0, 0, 0x7F7F7F7F, 0, 0x7F7F7F7F);
    }
    int rowb = rowbase + w * 64;
#pragma unroll
    for (int im = 0; im < 2; ++im) {
#pragma unroll
      for (int reg = 0; reg < 16; ++reg) {
        float a0 = acc[im][0][reg], a1 = acc[im][1][reg];
        float vo = half ? a1 : a0;
        float vs = half ? a0 : a1;
        float vr = __shfl_xor(vs, 32, 64);
        int rbase = rowb + im * 32 + (reg & 3) + 8 * (reg >> 2);
        ins8(list, packval(vo, rbase + 4 * half));
        ins8(list, packval(vr, rbase + 4 * (1 - half)));
      }
    }
  }
  __syncthreads();
  unsigned* M = (unsigned*)lds;
#pragma unroll
  for (int j = 0; j < 8; ++j) M[lane * 33 + w * 8 + j] = list[j];
  __syncthreads();
  if (t < 64) {
    unsigned bl[8];
#pragma unroll
    for (int j = 0; j < 8; ++j) bl[j] = 0u;
#pragma unroll 1
    for (int i = 0; i < 32; ++i) ins8(bl, M[t * 33 + i]);
    size_t base = (((size_t)b * 4 + sp) * 4096 + colbase + t) * 8;
#pragma unroll
    for (int j = 0; j < 8; ++j) pidx[base + j] = (int)bl[j];
  }
}

// ---- fp8-top-8 tournament, then exact f64 refine (R13-proven)
__global__ __launch_bounds__(256) void k_refine(const float* __restrict__ xt,
                                                const double* __restrict__ dinv,
                                                const int* __restrict__ pidx,
                                                float* __restrict__ Sval,
                                                int* __restrict__ Sidx) {
  int w = threadIdx.x >> 6, lane = threadIdx.x & 63;
  int gl = blockIdx.x * 4 + w;
  int b = gl >> 12, l = gl & 4095;
  int y = l >> 6, xq = l & 63;
  const float* xb = xt + ((size_t)b * 4096) * 64;
  unsigned cp = 0u;
  if (lane < 32) {
    int sp = lane >> 3, j = lane & 7;
    cp = (unsigned)pidx[(((size_t)b * 4 + sp) * 4096 + l) * 8 + j];
  }
  int wm[8];
#pragma unroll
  for (int r = 0; r < 8; ++r) {
    unsigned v = cp;
#pragma unroll
    for (int off = 32; off; off >>= 1) {
      unsigned ov = __shfl_xor(v, off, 64);
      v = ov > v ? ov : v;
    }
    wm[r] = (int)(v & 4095u);
    if (cp == v) cp = 0u;
  }
  int ch4 = (lane & 15) * 4;
  float4 xl4[9];
#pragma unroll
  for (int tap = 0; tap < 9; ++tap) {
    int kh = tap / 3, kw = tap % 3;
    xl4[tap] = *(const float4*)&xb[(refl(y + kh - 1) * 64 + refl(xq + kw - 1)) * 64 + ch4];
  }
  double il = dinv[b * 4096 + l];
  double rv = -1e30;
  int ridx = 0x7fffffff;
#pragma unroll
  for (int it = 0; it < 2; ++it) {
    int m = wm[it * 4 + (lane >> 4)];
    int my = m >> 6, mx = m & 63;
    double d = 0.0;
#pragma unroll
    for (int tap = 0; tap < 9; ++tap) {
      int kh = tap / 3, kw = tap % 3;
      float4 gv = *(const float4*)&xb[(refl(my + kh - 1) * 64 + refl(mx + kw - 1)) * 64 + ch4];
      d += (double)xl4[tap].x * (double)gv.x + (double)xl4[tap].y * (double)gv.y +
           (double)xl4[tap].z * (double)gv.z + (double)xl4[tap].w * (double)gv.w;
    }
#pragma unroll
    for (int off = 1; off < 16; off <<= 1) d += __shfl_xor(d, off, 64);
    double R = d * il * dinv[b * 4096 + m];
    double Rsrc = __shfl(R, (lane & 3) * 16, 64);
    int msrc = __shfl(m, (lane & 3) * 16, 64);
    if ((lane >> 2) == it && lane < 8) { rv = Rsrc; ridx = msrc; }
  }
#pragma unroll
  for (int r = 0; r < 5; ++r) {
    double v = rv;
    int i = ridx;
#pragma unroll
    for (int off = 32; off; off >>= 1) {
      double ov = __shfl_xor(v, off, 64);
      int oi = __shfl_xor(i, off, 64);
      if (ov > v || (ov == v && oi < i)) { v = ov; i = oi; }
    }
    if (r >= 1 && lane == 0) {
      Sval[((size_t)b * 5 + r) * 4096 + l] = (float)v;
      Sidx[((size_t)b * 5 + r) * 4096 + l] = i;
    }
    if (rv == v && ridx == i) rv = -1e30;
  }
}

// ---- texture gather -> 384-deep bf16 tiled input (feat|x|texture)
// 8 px/block, grid 2048, 8 blocks/CU for latency hiding.
__global__ __launch_bounds__(256, 8) void k_tex(const float* __restrict__ xt,
                                                const float* __restrict__ feat,
                                                const float* __restrict__ Sval,
                                                const int* __restrict__ Sidx,
                                                ushort_t* __restrict__ Xb16) {
  __shared__ ushort_t U[3072];
  __shared__ int SI[3 * 10 * 4];
  __shared__ float SV[8 * 4];
  int t = threadIdx.x;
  int w = t >> 6, lane = t & 63;
  int p0 = blockIdx.x * 8;
  int b = p0 >> 12, pl = p0 & 4095;
  int y0 = pl >> 6, x0 = pl & 63;
  if (t < 120) {
    int r = t / 40, rem = t % 40;
    int c = rem >> 2, i = (rem & 3) + 1;
    int qy = y0 - 1 + r, qx = x0 - 1 + c;
    int m = 0x7fffffff;
    if (qy >= 0 && qy < 64 && qx >= 0 && qx < 64)
      m = Sidx[((size_t)b * 5 + i) * 4096 + qy * 64 + qx] & 4095;
    SI[(r * 10 + c) * 4 + (i - 1)] = m;
  }
  if (t < 32) {
    int px = t >> 2, i = (t & 3) + 1;
    SV[px * 4 + (i - 1)] = Sval[((size_t)b * 5 + i) * 4096 + pl + px];
  }
#pragma unroll
  for (int jj = 0; jj < 2; ++jj) {
    int px = w * 2 + jj;
    float fv = feat[((size_t)b * 4096 + pl + px) * 64 + lane];
    float xv = xt[((size_t)b * 4096 + pl + px) * 64 + lane];
    __hip_bfloat16 hf = __float2bfloat16(fv);
    __hip_bfloat16 hx = __float2bfloat16(xv);
    U[toff(px, lane, 3072)] = *(ushort_t*)&hf;
    U[toff(px, 64 + lane, 3072)] = *(ushort_t*)&hx;
  }
  __syncthreads();
  const float* xb = xt + ((size_t)b * 4096) * 64;
#pragma unroll 8
  for (int k = 0; k < 8; ++k) {
    int pr = w * 8 + k;
    int px = pr >> 2, i = pr & 3;
    float a = 0.f;
#pragma unroll
    for (int tap = 0; tap < 9; ++tap) {
      int kh = tap / 3, kw = tap % 3;
      int m = SI[((2 - kh) * 10 + px + 2 - kw) * 4 + i];
      if (m != 0x7fffffff) {
        int gy = refl((m >> 6) + kh - 1), gx = refl((m & 63) + kw - 1);
        a += xb[(gy * 64 + gx) * 64 + lane];
      }
    }
    __hip_bfloat16 h = __float2bfloat16(a * SV[px * 4 + i] * (1.f / 9.f));
    U[toff(px, 128 + i * 64 + lane, 3072)] = *(ushort_t*)&h;
  }
  __syncthreads();
  ushort_t* g = Xb16 + (size_t)blockIdx.x * 3072;
  {
    *(uint4*)&g[t * 8] = *(const uint4*)&U[t * 8];
    if (t < 128) *(uint4*)&g[(256 + t) * 8] = *(const uint4*)&U[(256 + t) * 8];
  }
}

// ---- final 1x1: bf16 MFMA GEMM K=384 (A,B pre-tiled), NCHW via LDS transpose
__global__ __launch_bounds__(256) void k_outg(const ushort_t* __restrict__ Xb16,
                                              const ushort_t* __restrict__ Wcatb,
                                              const float* __restrict__ beff,
                                              float* __restrict__ out) {
  __shared__ __align__(16) ushort_t Ab[2][2048];
  __shared__ __align__(16) ushort_t Bb[2][2048];
  __shared__ float T[64 * 65];
  int t = threadIdx.x;
  int w = t >> 6, lane = t & 63, rr = lane & 31, half = lane >> 5;
  int mi = w >> 1, ni = w & 1;
  int bid = blockIdx.x;
  int b = bid >> 6, y = bid & 63;
  const ushort_t* XA = Xb16 + (size_t)bid * 24576;  // 8 rbs x 3072

  float bz = beff[ni * 32 + rr];
  f32x16 acc;
#pragma unroll
  for (int q = 0; q < 16; ++q) acc[q] = bz;

#define STAGE_OUT(kc_, buf_)                                                    \
  {                                                                             \
    gload_lds16(XA + (size_t)(t >> 5) * 3072 + (kc_) * 256 + (t & 31) * 8,      \
                &Ab[buf_][t * 8]);                                              \
    gload_lds16(Wcatb + (size_t)(t >> 5) * 3072 + (kc_) * 256 + (t & 31) * 8,   \
                &Bb[buf_][t * 8]);                                              \
  }

  STAGE_OUT(0, 0)
#pragma unroll 2
  for (int kc = 0; kc < 12; ++kc) {
    __syncthreads();
    if (kc < 11) STAGE_OUT(kc + 1, (kc + 1) & 1)
    const ushort_t* tA = Ab[kc & 1];
    const ushort_t* tB = Bb[kc & 1];
#pragma unroll
    for (int ks = 0; ks < 2; ++ks) {
      int seg8 = (ks * 2 + half) * 8 + (rr & 7);
      short8 af = *(const short8*)&tA[(mi * 4 + (rr >> 3)) * 256 + seg8 * 8];
      short8 bf = *(const short8*)&tB[(ni * 4 + (rr >> 3)) * 256 + seg8 * 8];
      acc = __builtin_amdgcn_mfma_f32_32x32x16_bf16(af, bf, acc, 0, 0, 0);
    }
  }
#undef STAGE_OUT
  __syncthreads();
  int n = ni * 32 + rr;
#pragma unroll
  for (int reg = 0; reg < 16; ++reg) {
    int m = mi * 32 + (reg & 3) + 8 * (reg >> 2) + 4 * half;
    T[m * 65 + n] = acc[reg];
  }
  __syncthreads();
  int n2 = t >> 2, grp = t & 3;
  float o[16];
#pragma unroll
  for (int j = 0; j < 16; ++j) o[j] = T[(grp * 16 + j) * 65 + n2];
  float* od = out + ((size_t)b * 64 + n2) * 4096 + y * 64 + grp * 16;
#pragma unroll
  for (int j = 0; j < 4; ++j) *(float4*)(od + j * 4) = *(float4*)&o[j * 4];
}

// ---------------------------------------------------------------------- launch
extern "C" void kernel_launch(void* const* d_in, const int* in_sizes, int n_in,
                              void* d_out, int out_size, void* d_ws, size_t ws_size,
                              hipStream_t stream) {
  const float* x = (const float*)d_in[0];
  const float* w1 = (const float*)d_in[1];
  const float* b1 = (const float*)d_in[2];
  const float* w2 = (const float*)d_in[3];
  const float* b2 = (const float*)d_in[4];
  const float* wt1 = (const float*)d_in[5];
  const float* bt1 = (const float*)d_in[6];
  const float* wt2 = (const float*)d_in[7];
  const float* bt2 = (const float*)d_in[8];

  char* ws = (char*)d_ws;
  float* x_t = (float*)(ws + 0);                       //  4 MB NHWC x
  float* y1 = (float*)(ws + 4194304);                  //  4 MB relu(conv1)
  float* feat = (float*)(ws + 8388608);                //  4 MB conv2
  uint8_t* Xq = (uint8_t*)(ws + 12582912);             //  9.4 MB fp8 qn unfold
  ushort_t* Xb16 = (ushort_t*)(ws + 12582912);         // 12.6 MB (aliases Xq —
                                                       //  written after gram)
  double* dinv = (double*)(ws + 31457280);             // 128 KB f64 1/norm
  int* pidx = (int*)(ws + 31653888);                   //  2 MB
  float* Sval = (float*)(ws + 33751040);               // 320 KB
  int* Sidx = (int*)(ws + 34078720);                   // 320 KB
  ushort_t* Wb1t = (ushort_t*)(ws + 34406400);         // 72 KB bf16 tiled W1
  ushort_t* Wb2t = (ushort_t*)(ws + 34553856);         // 72 KB bf16 tiled W2
  ushort_t* Wcatb = (ushort_t*)(ws + 34701312);        // 48 KB bf16 tiled Wcat
  float* beff = (float*)(ws + 34799616);               // 256 B
  float* out = (float*)d_out;

  k_prep<<<dim3(641), dim3(256), 0, stream>>>(x, x_t, w1, w2, wt1, bt1, wt2, bt2,
                                              Wb1t, Wb2t, Wcatb, beff);
  k_fuseA<<<dim3(2304), dim3(256), 0, stream>>>(x_t, Xq, dinv, Wb1t, b1, y1);
  k_cgemm<<<dim3(256), dim3(256), 0, stream>>>(y1, Wb2t, b2, feat, 0);
  k_gram<<<dim3(1024), dim3(256), 0, stream>>>(Xq, pidx);
  k_refine<<<dim3(4096), dim3(256), 0, stream>>>(x_t, dinv, pidx, Sval, Sidx);
  k_tex<<<dim3(2048), dim3(256), 0, stream>>>(x_t, feat, Sval, Sidx, Xb16);
  k_outg<<<dim3(256), dim3(256), 0, stream>>>(Xb16, Wcatb, beff, out);
}